// Round 4
// baseline (1207.836 us; speedup 1.0000x reference)
//
#include <hip/hip_runtime.h>

// ---------------------------------------------------------------------------
// DIEN forward on MI355X (gfx950).  B=1024, T=200, E=128, H=128.
// Inputs: fp32 (confirmed by runtime discriminator round 3); a bf16 fallback
// path is kept via dtype dispatch on ln_g1 (= ones).
// Compute: bf16 MFMA + fp32 accum.  OUTPUT: fp32 (reference output dtype).
// d_out (fp32): [0,3072) preds (B,3); [3072,3072+B*199) aux.
// Workspace: HS 52.4MB + SC + CAND + XF = 54.2 MB.
// ---------------------------------------------------------------------------

typedef __bf16 bf16;
typedef float f32x4 __attribute__((ext_vector_type(4)));
typedef __bf16 bf16x8 __attribute__((ext_vector_type(8)));
typedef __bf16 bf16x4 __attribute__((ext_vector_type(4)));

#define MFMA16(a, b, c) __builtin_amdgcn_mfma_f32_16x16x32_bf16((a), (b), (c), 0, 0, 0)

#define BATCH 1024
#define SEQT 200
#define F32_ONE 0x3F800000u

__device__ __forceinline__ float sigm(float x) { return 1.0f / (1.0f + __expf(-x)); }
__device__ __forceinline__ float tanh_fast(float x) {
  float ax = fabsf(x);
  float e = __expf(2.0f * ax);          // overflow -> inf -> 2/inf = 0 -> 1
  float t = 1.0f - 2.0f / (e + 1.0f);
  return copysignf(t, x);
}

// ---- dtype-generic loads ---------------------------------------------------
template <typename DT> __device__ __forceinline__ float ldf(const DT* p, long i);
template <> __device__ __forceinline__ float ldf<bf16>(const bf16* p, long i) { return (float)p[i]; }
template <> __device__ __forceinline__ float ldf<float>(const float* p, long i) { return p[i]; }

template <typename DT> __device__ __forceinline__ bf16x8 ld8(const DT* p, long i);
template <> __device__ __forceinline__ bf16x8 ld8<bf16>(const bf16* p, long i) {
  return *(const bf16x8*)(p + i);
}
template <> __device__ __forceinline__ bf16x8 ld8<float>(const float* p, long i) {
  f32x4 a = *(const f32x4*)(p + i);
  f32x4 b = *(const f32x4*)(p + i + 4);
  bf16x8 r;
  r[0] = (bf16)a[0]; r[1] = (bf16)a[1]; r[2] = (bf16)a[2]; r[3] = (bf16)a[3];
  r[4] = (bf16)b[0]; r[5] = (bf16)b[1]; r[6] = (bf16)b[2]; r[7] = (bf16)b[3];
  return r;
}

// ---------------------------------------------------------------------------
// prep: candidate gather, category gather, dense projection -> xfinal tail
// ---------------------------------------------------------------------------
template <typename DT>
__device__ __forceinline__ void prep_body(
    const int* __restrict__ cid, const int* __restrict__ ccat,
    const DT* __restrict__ dense, const DT* __restrict__ item_emb,
    const DT* __restrict__ cat_emb, const DT* __restrict__ dp_w,
    const DT* __restrict__ dp_b, bf16* __restrict__ candbuf, bf16* __restrict__ xf) {
  const int b = blockIdx.x;
  const int t = threadIdx.x;
  bf16 v = (bf16)ldf(item_emb, (long)cid[b] * 128 + t);
  candbuf[b * 128 + t] = v;
  xf[(long)b * 352 + 128 + t] = v;
  if (t < 64) xf[(long)b * 352 + 256 + t] = (bf16)ldf(cat_emb, (long)ccat[b] * 64 + t);
  if (t < 32) {
    float s = ldf(dp_b, t);
    for (int k = 0; k < 5; k++) s += ldf(dense, b * 5 + k) * ldf(dp_w, t * 5 + k);
    xf[(long)b * 352 + 320 + t] = (bf16)s;
  }
}
__global__ __launch_bounds__(128) void k_prep(
    const unsigned* __restrict__ disc, const int* cid, const int* ccat,
    const void* dense, const void* item_emb, const void* cat_emb,
    const void* dp_w, const void* dp_b, bf16* candbuf, bf16* xf) {
  if (*disc == F32_ONE)
    prep_body<float>(cid, ccat, (const float*)dense, (const float*)item_emb,
                     (const float*)cat_emb, (const float*)dp_w, (const float*)dp_b, candbuf, xf);
  else
    prep_body<bf16>(cid, ccat, (const bf16*)dense, (const bf16*)item_emb,
                    (const bf16*)cat_emb, (const bf16*)dp_w, (const bf16*)dp_b, candbuf, xf);
}

// ---------------------------------------------------------------------------
// GRU scan, x-projection fused. 16 batch rows/block, block 512 (8 waves).
// ---------------------------------------------------------------------------
template <typename DT>
__device__ __forceinline__ void gru_body(
    const int* __restrict__ ids, const DT* __restrict__ item_emb,
    const DT* __restrict__ wih, const DT* __restrict__ whh,
    const DT* __restrict__ bih, const DT* __restrict__ bhh, bf16* __restrict__ hs,
    bf16 (*xL)[136], bf16 (*hA)[136], float (*hp)[520]) {
  const int b0 = blockIdx.x * 16;
  const int tid = threadIdx.x;
  const int w = tid >> 6, lane = tid & 63, l15 = lane & 15, quad = lane >> 4;

  for (int i = tid; i < 16 * 136; i += 512) ((bf16*)hA)[i] = (bf16)0.0f;

  // register-cached weight fragments: wave w owns output cols 16w..16w+15
  bf16x8 wir[4], wiz[4], win_[4], whr[4], whz[4], whn[4];
  {
    const long nr = w * 16 + l15;
#pragma unroll
    for (int k = 0; k < 4; k++) {
      const long off = k * 32 + quad * 8;
      wir[k] = ld8(wih, nr * 128 + off);
      wiz[k] = ld8(wih, (128 + nr) * 128 + off);
      win_[k] = ld8(wih, (256 + nr) * 128 + off);
      whr[k] = ld8(whh, nr * 128 + off);
      whz[k] = ld8(whh, (128 + nr) * 128 + off);
      whn[k] = ld8(whh, (256 + nr) * 128 + off);
    }
  }

  // prefetch pipeline (waves 0..3): thread -> (row, 8-elem chunk)
  const int row = tid >> 4, ch = tid & 15;
  long ib = 0; int idn = 0; bf16x8 pf;
  if (tid < 256) {
    ib = (long)(b0 + row) * SEQT;
    int id0 = ids[ib];
    *(bf16x8*)&xL[row][ch * 8] = ld8(item_emb, (long)id0 * 128 + ch * 8);
    idn = ids[ib + 1];
  }

  const int er = tid >> 5;
  const int ec = (tid & 31) * 4;
  float br_[4], bz_[4], bxn_[4], bhn_[4];
#pragma unroll
  for (int j = 0; j < 4; j++) {
    br_[j] = ldf(bih, ec + j) + ldf(bhh, ec + j);
    bz_[j] = ldf(bih, 128 + ec + j) + ldf(bhh, 128 + ec + j);
    bxn_[j] = ldf(bih, 256 + ec + j);
    bhn_[j] = ldf(bhh, 256 + ec + j);
  }
  const f32x4 z4 = {0.f, 0.f, 0.f, 0.f};
  __syncthreads();

  for (int t = 0; t < SEQT; t++) {
    if (tid < 256) {
      if (t + 1 < SEQT) pf = ld8(item_emb, (long)idn * 128 + ch * 8);
      if (t + 2 < SEQT) idn = ids[ib + t + 2];
    }
    bf16x8 af[4], xfr[4];
#pragma unroll
    for (int k = 0; k < 4; k++) {
      af[k] = *(const bf16x8*)&hA[l15][k * 32 + quad * 8];
      xfr[k] = *(const bf16x8*)&xL[l15][k * 32 + quad * 8];
    }
    f32x4 ar = z4, az = z4, axn = z4, ahn = z4;
#pragma unroll
    for (int k = 0; k < 4; k++) {
      ar = MFMA16(xfr[k], wir[k], ar);  ar = MFMA16(af[k], whr[k], ar);
      az = MFMA16(xfr[k], wiz[k], az);  az = MFMA16(af[k], whz[k], az);
      axn = MFMA16(xfr[k], win_[k], axn);
      ahn = MFMA16(af[k], whn[k], ahn);
    }
    const int nc = w * 16 + l15;
#pragma unroll
    for (int r = 0; r < 4; r++) {
      hp[quad * 4 + r][nc] = ar[r];
      hp[quad * 4 + r][128 + nc] = az[r];
      hp[quad * 4 + r][256 + nc] = axn[r];
      hp[quad * 4 + r][384 + nc] = ahn[r];
    }
    __syncthreads();

    bf16x4 hv;
#pragma unroll
    for (int j = 0; j < 4; j++) {
      float r_ = sigm(hp[er][ec + j] + br_[j]);
      float z_ = sigm(hp[er][128 + ec + j] + bz_[j]);
      float n_ = tanh_fast(hp[er][256 + ec + j] + bxn_[j] + r_ * (hp[er][384 + ec + j] + bhn_[j]));
      float hold = (float)hA[er][ec + j];
      hv[j] = (bf16)((1.0f - z_) * n_ + z_ * hold);
    }
    *(bf16x4*)&hA[er][ec] = hv;
    *(bf16x4*)(hs + ((long)(b0 + er) * SEQT + t) * 128 + ec) = hv;
    if (tid < 256 && t + 1 < SEQT) *(bf16x8*)&xL[row][ch * 8] = pf;
    __syncthreads();
  }
}
__global__ __launch_bounds__(512) void k_gru(
    const unsigned* __restrict__ disc, const int* ids, const void* item_emb,
    const void* wih, const void* whh, const void* bih, const void* bhh, bf16* hs) {
  __shared__ bf16 xL[16][136];
  __shared__ bf16 hA[16][136];
  __shared__ float hp[16][520];
  if (*disc == F32_ONE)
    gru_body<float>(ids, (const float*)item_emb, (const float*)wih, (const float*)whh,
                    (const float*)bih, (const float*)bhh, hs, xL, hA, hp);
  else
    gru_body<bf16>(ids, (const bf16*)item_emb, (const bf16*)wih, (const bf16*)whh,
                   (const bf16*)bih, (const bf16*)bhh, hs, xL, hA, hp);
}

// ---------------------------------------------------------------------------
// aux head: relu(hs[:, :199] @ w1^T + b1) @ w2^T + b2 (fused N=1 reduction).
// Output fp32.
// ---------------------------------------------------------------------------
template <typename DT>
__device__ __forceinline__ void aux_body(
    const bf16* __restrict__ hs, const DT* __restrict__ w1, const DT* __restrict__ b1v,
    const DT* __restrict__ w2v, const DT* __restrict__ b2v, float* __restrict__ outaux,
    bf16 (*As)[136], bf16 (*Ws)[136]) {
  const int b = blockIdx.y;
  const int t0 = blockIdx.x * 64;
  const int tid = threadIdx.x;
#pragma unroll
  for (int j = 0; j < 4; j++) {
    int ci = j * 256 + tid;
    int row = ci >> 4, k8 = (ci & 15) * 8;
    int t = t0 + row; int tc = t < 199 ? t : 198;
    *(bf16x8*)&As[row][k8] = *(const bf16x8*)(hs + ((long)b * SEQT + tc) * 128 + k8);
  }
#pragma unroll
  for (int j = 0; j < 8; j++) {
    int ci = j * 256 + tid;
    int row = ci >> 4, k8 = (ci & 15) * 8;
    *(bf16x8*)&Ws[row][k8] = ld8(w1, (long)row * 128 + k8);
  }
  __syncthreads();
  const int w = tid >> 6, lane = tid & 63, l15 = lane & 15, quad = lane >> 4;
  bf16x8 af[4];
#pragma unroll
  for (int k = 0; k < 4; k++) af[k] = *(const bf16x8*)&As[w * 16 + l15][k * 32 + quad * 8];
  const f32x4 z4 = {0.f, 0.f, 0.f, 0.f};
  float part[4] = {0.f, 0.f, 0.f, 0.f};
#pragma unroll
  for (int nt = 0; nt < 8; nt++) {
    f32x4 acc = z4;
#pragma unroll
    for (int k = 0; k < 4; k++) {
      bf16x8 bfr = *(const bf16x8*)&Ws[nt * 16 + l15][k * 32 + quad * 8];
      acc = MFMA16(af[k], bfr, acc);
    }
    int n = nt * 16 + l15;
    float b1f = ldf(b1v, n), w2f = ldf(w2v, n);
#pragma unroll
    for (int r = 0; r < 4; r++) {
      float y = acc[r] + b1f;
      part[r] += (y > 0.f ? y : 0.f) * w2f;
    }
  }
#pragma unroll
  for (int m = 1; m < 16; m <<= 1)
#pragma unroll
    for (int r = 0; r < 4; r++) part[r] += __shfl_xor(part[r], m, 64);
  if (l15 == 0) {
    float b2 = ldf(b2v, 0);
#pragma unroll
    for (int r = 0; r < 4; r++) {
      int t = t0 + w * 16 + quad * 4 + r;
      if (t < 199) outaux[(long)b * 199 + t] = part[r] + b2;
    }
  }
}
__global__ __launch_bounds__(256) void k_aux(
    const unsigned* __restrict__ disc, const bf16* hs, const void* w1, const void* b1v,
    const void* w2v, const void* b2v, float* outaux) {
  __shared__ bf16 As[64][136];
  __shared__ bf16 Ws[128][136];
  if (*disc == F32_ONE)
    aux_body<float>(hs, (const float*)w1, (const float*)b1v, (const float*)w2v,
                    (const float*)b2v, outaux, As, Ws);
  else
    aux_body<bf16>(hs, (const bf16*)w1, (const bf16*)b1v, (const bf16*)w2v,
                   (const bf16*)b2v, outaux, As, Ws);
}

// ---------------------------------------------------------------------------
// attention scores: prelu([hs,cand,hs*cand] @ w1^T + b1, a) @ w2^T + b2.
// ---------------------------------------------------------------------------
template <typename DT>
__device__ __forceinline__ void att_body(
    const bf16* __restrict__ hs, const bf16* __restrict__ cand,
    const DT* __restrict__ w1, const DT* __restrict__ b1v, const DT* __restrict__ a_s,
    const DT* __restrict__ w2v, const DT* __restrict__ b2v, float* __restrict__ scores,
    bf16 (*As)[392]) {
  const int b = blockIdx.y;
  const int t0 = blockIdx.x * 64;
  const int tid = threadIdx.x;
#pragma unroll
  for (int j = 0; j < 12; j++) {
    int ci = j * 256 + tid;
    int row = ci / 48;
    int k8 = (ci % 48) * 8;
    int t = t0 + row; int tc = t < SEQT ? t : SEQT - 1;
    const bf16* hrow = hs + ((long)b * SEQT + tc) * 128;
    bf16x8 v;
    if (k8 < 128) v = *(const bf16x8*)(hrow + k8);
    else if (k8 < 256) v = *(const bf16x8*)(cand + b * 128 + (k8 - 128));
    else {
      bf16x8 hv = *(const bf16x8*)(hrow + (k8 - 256));
      bf16x8 cv = *(const bf16x8*)(cand + b * 128 + (k8 - 256));
#pragma unroll
      for (int q = 0; q < 8; q++) v[q] = (bf16)((float)hv[q] * (float)cv[q]);
    }
    *(bf16x8*)&As[row][k8] = v;
  }
  __syncthreads();
  const int w = tid >> 6, lane = tid & 63, l15 = lane & 15, quad = lane >> 4;
  const f32x4 z4 = {0.f, 0.f, 0.f, 0.f};
  f32x4 acc[4] = {z4, z4, z4, z4};
  for (int k = 0; k < 12; k++) {
    bf16x8 af = *(const bf16x8*)&As[w * 16 + l15][k * 32 + quad * 8];
#pragma unroll
    for (int nt = 0; nt < 4; nt++) {
      bf16x8 bfr = ld8(w1, (long)(nt * 16 + l15) * 384 + k * 32 + quad * 8);
      acc[nt] = MFMA16(af, bfr, acc[nt]);
    }
  }
  float aP = ldf(a_s, 0);
  float part[4] = {0.f, 0.f, 0.f, 0.f};
#pragma unroll
  for (int nt = 0; nt < 4; nt++) {
    int n = nt * 16 + l15;
    float b1f = ldf(b1v, n), w2f = ldf(w2v, n);
#pragma unroll
    for (int r = 0; r < 4; r++) {
      float y = acc[nt][r] + b1f;
      y = (y >= 0.f) ? y : aP * y;
      part[r] += y * w2f;
    }
  }
#pragma unroll
  for (int m = 1; m < 16; m <<= 1)
#pragma unroll
    for (int r = 0; r < 4; r++) part[r] += __shfl_xor(part[r], m, 64);
  if (l15 == 0) {
    float b2 = ldf(b2v, 0);
#pragma unroll
    for (int r = 0; r < 4; r++) {
      int t = t0 + w * 16 + quad * 4 + r;
      if (t < SEQT) scores[(long)b * SEQT + t] = part[r] + b2;
    }
  }
}
__global__ __launch_bounds__(256) void k_att(
    const unsigned* __restrict__ disc, const bf16* hs, const bf16* cand,
    const void* w1, const void* b1v, const void* a_s,
    const void* w2v, const void* b2v, float* scores) {
  __shared__ bf16 As[64][392];
  if (*disc == F32_ONE)
    att_body<float>(hs, cand, (const float*)w1, (const float*)b1v, (const float*)a_s,
                    (const float*)w2v, (const float*)b2v, scores, As);
  else
    att_body<bf16>(hs, cand, (const bf16*)w1, (const bf16*)b1v, (const bf16*)a_s,
                   (const bf16*)w2v, (const bf16*)b2v, scores, As);
}

// ---------------------------------------------------------------------------
// softmax over T=200, in place on fp32 scores.
// ---------------------------------------------------------------------------
__global__ __launch_bounds__(256) void k_softmax(float* __restrict__ sc) {
  const int b = blockIdx.x, tid = threadIdx.x;
  __shared__ float red[256];
  float v = (tid < SEQT) ? sc[(long)b * SEQT + tid] : -1e30f;
  red[tid] = v; __syncthreads();
  for (int s = 128; s > 0; s >>= 1) { if (tid < s) red[tid] = fmaxf(red[tid], red[tid + s]); __syncthreads(); }
  float mx = red[0]; __syncthreads();
  float e = (tid < SEQT) ? __expf(v - mx) : 0.f;
  red[tid] = e; __syncthreads();
  for (int s = 128; s > 0; s >>= 1) { if (tid < s) red[tid] += red[tid + s]; __syncthreads(); }
  float inv = 1.0f / red[0];
  if (tid < SEQT) sc[(long)b * SEQT + tid] = e * inv;
}

// ---------------------------------------------------------------------------
// AUGRU scan, x-projection fused (x = hs[:,t]). 16 rows/block, block 512.
// ---------------------------------------------------------------------------
template <typename DT>
__device__ __forceinline__ void augru_body(
    const bf16* __restrict__ hsrc, const float* __restrict__ att,
    const DT* __restrict__ wz, const DT* __restrict__ wr, const DT* __restrict__ wh,
    const DT* __restrict__ bzv, const DT* __restrict__ brv, const DT* __restrict__ bhv,
    bf16* __restrict__ xf_out,
    bf16 (*xA)[136], bf16 (*hA)[136], bf16 (*rhA)[136], float (*hp)[520], float (*zpb)[132]) {
  const int b0 = blockIdx.x * 16;
  const int tid = threadIdx.x;
  const int w = tid >> 6, lane = tid & 63, l15 = lane & 15, quad = lane >> 4;

  for (int i = tid; i < 16 * 136; i += 512) ((bf16*)hA)[i] = (bf16)0.0f;

  bf16x8 wzx[4], wzh[4], wrx[4], wrh[4], whx[4], whh_[4];
  {
    const long nr = w * 16 + l15;
#pragma unroll
    for (int k = 0; k < 4; k++) {
      const long off = k * 32 + quad * 8;
      wzx[k] = ld8(wz, nr * 256 + off);
      wzh[k] = ld8(wz, nr * 256 + 128 + off);
      wrx[k] = ld8(wr, nr * 256 + off);
      wrh[k] = ld8(wr, nr * 256 + 128 + off);
      whx[k] = ld8(wh, nr * 256 + off);
      whh_[k] = ld8(wh, nr * 256 + 128 + off);
    }
  }

  const int row = tid >> 4, ch = tid & 15;
  bf16x8 pf;
  if (tid < 256)
    *(bf16x8*)&xA[row][ch * 8] = *(const bf16x8*)(hsrc + ((long)(b0 + row) * SEQT) * 128 + ch * 8);

  const int er = tid >> 5;
  const int ec = (tid & 31) * 4;
  const long rb_e = (long)(b0 + er) * SEQT;
  float bz_[4], br_[4], bh_[4];
#pragma unroll
  for (int j = 0; j < 4; j++) {
    bz_[j] = ldf(bzv, ec + j);
    br_[j] = ldf(brv, ec + j);
    bh_[j] = ldf(bhv, ec + j);
  }
  const f32x4 z4 = {0.f, 0.f, 0.f, 0.f};
  __syncthreads();

  for (int t = 0; t < SEQT; t++) {
    if (tid < 256 && t + 1 < SEQT)
      pf = *(const bf16x8*)(hsrc + ((long)(b0 + row) * SEQT + t + 1) * 128 + ch * 8);
    float a_ = att[rb_e + t];

    // ---- phase A
    bf16x8 af[4], xfr[4];
#pragma unroll
    for (int k = 0; k < 4; k++) {
      af[k] = *(const bf16x8*)&hA[l15][k * 32 + quad * 8];
      xfr[k] = *(const bf16x8*)&xA[l15][k * 32 + quad * 8];
    }
    f32x4 acz = z4, acr = z4, axh = z4;
#pragma unroll
    for (int k = 0; k < 4; k++) {
      acz = MFMA16(xfr[k], wzx[k], acz);  acz = MFMA16(af[k], wzh[k], acz);
      acr = MFMA16(xfr[k], wrx[k], acr);  acr = MFMA16(af[k], wrh[k], acr);
      axh = MFMA16(xfr[k], whx[k], axh);
    }
    const int nc = w * 16 + l15;
#pragma unroll
    for (int r = 0; r < 4; r++) {
      hp[quad * 4 + r][nc] = acz[r];
      hp[quad * 4 + r][128 + nc] = acr[r];
      hp[quad * 4 + r][256 + nc] = axh[r];
    }
    __syncthreads();

    // ---- phase B: gates, r*h
    bf16x4 rhv;
#pragma unroll
    for (int j = 0; j < 4; j++) {
      float z_ = sigm(hp[er][ec + j] + bz_[j]);
      float r_ = sigm(hp[er][128 + ec + j] + br_[j]);
      zpb[er][ec + j] = a_ * z_;
      rhv[j] = (bf16)(r_ * (float)hA[er][ec + j]);
    }
    *(bf16x4*)&rhA[er][ec] = rhv;
    __syncthreads();

    // ---- phase C: hh GEMM
    bf16x8 rf[4];
#pragma unroll
    for (int k = 0; k < 4; k++) rf[k] = *(const bf16x8*)&rhA[l15][k * 32 + quad * 8];
    f32x4 ahh = z4;
#pragma unroll
    for (int k = 0; k < 4; k++) ahh = MFMA16(rf[k], whh_[k], ahh);
#pragma unroll
    for (int r = 0; r < 4; r++) hp[quad * 4 + r][384 + nc] = ahh[r];
    __syncthreads();

    // ---- phase D: candidate + gated update
    bf16x4 hvn;
#pragma unroll
    for (int j = 0; j < 4; j++) {
      float ht = tanh_fast(hp[er][256 + ec + j] + bh_[j] + hp[er][384 + ec + j]);
      float zp = zpb[er][ec + j];
      float hold = (float)hA[er][ec + j];
      hvn[j] = (bf16)((1.f - zp) * hold + zp * ht);
    }
    *(bf16x4*)&hA[er][ec] = hvn;
    if (t == SEQT - 1) *(bf16x4*)(xf_out + (long)(b0 + er) * 352 + ec) = hvn;
    if (tid < 256 && t + 1 < SEQT) *(bf16x8*)&xA[row][ch * 8] = pf;
    __syncthreads();
  }
}
__global__ __launch_bounds__(512) void k_augru(
    const unsigned* __restrict__ disc, const bf16* hsrc, const float* att,
    const void* wz, const void* wr, const void* wh,
    const void* bzv, const void* brv, const void* bhv, bf16* xf_out) {
  __shared__ bf16 xA[16][136];
  __shared__ bf16 hA[16][136];
  __shared__ bf16 rhA[16][136];
  __shared__ float hp[16][520];
  __shared__ float zpb[16][132];
  if (*disc == F32_ONE)
    augru_body<float>(hsrc, att, (const float*)wz, (const float*)wr, (const float*)wh,
                      (const float*)bzv, (const float*)brv, (const float*)bhv, xf_out,
                      xA, hA, rhA, hp, zpb);
  else
    augru_body<bf16>(hsrc, att, (const bf16*)wz, (const bf16*)wr, (const bf16*)wh,
                     (const bf16*)bzv, (const bf16*)brv, (const bf16*)bhv, xf_out,
                     xA, hA, rhA, hp, zpb);
}

// ---------------------------------------------------------------------------
// final MLP: 352->256->128->64 (LN+prelu each) -> 3 heads (sigmoid, fp32 out).
// One wave per batch row; grid 256 x block 256.
// ---------------------------------------------------------------------------
template <typename DT>
__device__ __forceinline__ void mlp_body(
    const bf16* __restrict__ xf,
    const DT* __restrict__ w1, const DT* __restrict__ b1, const DT* __restrict__ g1, const DT* __restrict__ be1, const DT* __restrict__ pa1,
    const DT* __restrict__ w2, const DT* __restrict__ b2, const DT* __restrict__ g2, const DT* __restrict__ be2, const DT* __restrict__ pa2,
    const DT* __restrict__ w3, const DT* __restrict__ b3, const DT* __restrict__ g3, const DT* __restrict__ be3, const DT* __restrict__ pa3,
    const DT* __restrict__ hw, const DT* __restrict__ hb, float* __restrict__ preds,
    float (*xs)[352], float (*ys)[256]) {
  const int tid = threadIdx.x, w = tid >> 6, lane = tid & 63;
  const int b = blockIdx.x * 4 + w;
  for (int i = lane; i < 352; i += 64) xs[w][i] = (float)xf[(long)b * 352 + i];
  __syncthreads();
  // layer 1: 352 -> 256
  float acc1[4];
#pragma unroll
  for (int oi = 0; oi < 4; oi++) {
    int o = lane + 64 * oi;
    float s = ldf(b1, o);
    for (int k = 0; k < 352; k += 8) {
      bf16x8 wv = ld8(w1, (long)o * 352 + k);
#pragma unroll
      for (int j = 0; j < 8; j++) s += xs[w][k + j] * (float)wv[j];
    }
    acc1[oi] = s;
  }
  float sm = acc1[0] + acc1[1] + acc1[2] + acc1[3];
#pragma unroll
  for (int m = 1; m < 64; m <<= 1) sm += __shfl_xor(sm, m, 64);
  float mean = sm * (1.0f / 256.0f);
  float vs = 0.f;
#pragma unroll
  for (int oi = 0; oi < 4; oi++) { float d = acc1[oi] - mean; vs += d * d; }
#pragma unroll
  for (int m = 1; m < 64; m <<= 1) vs += __shfl_xor(vs, m, 64);
  float rstd = rsqrtf(vs * (1.0f / 256.0f) + 1e-5f);
  float a1 = ldf(pa1, 0);
#pragma unroll
  for (int oi = 0; oi < 4; oi++) {
    int o = lane + 64 * oi;
    float y = (acc1[oi] - mean) * rstd * ldf(g1, o) + ldf(be1, o);
    ys[w][o] = (y >= 0.f) ? y : a1 * y;
  }
  __syncthreads();
  // layer 2: 256 -> 128
  float acc2[2];
#pragma unroll
  for (int oi = 0; oi < 2; oi++) {
    int o = lane + 64 * oi;
    float s = ldf(b2, o);
    for (int k = 0; k < 256; k += 8) {
      bf16x8 wv = ld8(w2, (long)o * 256 + k);
#pragma unroll
      for (int j = 0; j < 8; j++) s += ys[w][k + j] * (float)wv[j];
    }
    acc2[oi] = s;
  }
  sm = acc2[0] + acc2[1];
#pragma unroll
  for (int m = 1; m < 64; m <<= 1) sm += __shfl_xor(sm, m, 64);
  mean = sm * (1.0f / 128.0f);
  vs = 0.f;
#pragma unroll
  for (int oi = 0; oi < 2; oi++) { float d = acc2[oi] - mean; vs += d * d; }
#pragma unroll
  for (int m = 1; m < 64; m <<= 1) vs += __shfl_xor(vs, m, 64);
  rstd = rsqrtf(vs * (1.0f / 128.0f) + 1e-5f);
  float a2 = ldf(pa2, 0);
  __syncthreads();
#pragma unroll
  for (int oi = 0; oi < 2; oi++) {
    int o = lane + 64 * oi;
    float y = (acc2[oi] - mean) * rstd * ldf(g2, o) + ldf(be2, o);
    xs[w][o] = (y >= 0.f) ? y : a2 * y;
  }
  __syncthreads();
  // layer 3: 128 -> 64
  float s3 = ldf(b3, lane);
  for (int k = 0; k < 128; k += 8) {
    bf16x8 wv = ld8(w3, (long)lane * 128 + k);
#pragma unroll
    for (int j = 0; j < 8; j++) s3 += xs[w][k + j] * (float)wv[j];
  }
  sm = s3;
#pragma unroll
  for (int m = 1; m < 64; m <<= 1) sm += __shfl_xor(sm, m, 64);
  mean = sm * (1.0f / 64.0f);
  float d3 = s3 - mean;
  vs = d3 * d3;
#pragma unroll
  for (int m = 1; m < 64; m <<= 1) vs += __shfl_xor(vs, m, 64);
  rstd = rsqrtf(vs * (1.0f / 64.0f) + 1e-5f);
  float a3 = ldf(pa3, 0);
  float y3 = d3 * rstd * ldf(g3, lane) + ldf(be3, lane);
  y3 = (y3 >= 0.f) ? y3 : a3 * y3;
  ys[w][lane] = y3;
  __syncthreads();
  if (lane < 3) {
    float s = ldf(hb, lane);
    for (int k = 0; k < 64; k++) s += ys[w][k] * ldf(hw, lane * 64 + k);
    preds[(long)b * 3 + lane] = sigm(s);
  }
}
__global__ __launch_bounds__(256) void k_mlp(
    const unsigned* __restrict__ disc, const bf16* xf,
    const void* w1, const void* b1, const void* g1, const void* be1, const void* pa1,
    const void* w2, const void* b2, const void* g2, const void* be2, const void* pa2,
    const void* w3, const void* b3, const void* g3, const void* be3, const void* pa3,
    const void* hw, const void* hb, float* preds) {
  __shared__ float xs[4][352];
  __shared__ float ys[4][256];
  if (*disc == F32_ONE)
    mlp_body<float>(xf,
        (const float*)w1, (const float*)b1, (const float*)g1, (const float*)be1, (const float*)pa1,
        (const float*)w2, (const float*)b2, (const float*)g2, (const float*)be2, (const float*)pa2,
        (const float*)w3, (const float*)b3, (const float*)g3, (const float*)be3, (const float*)pa3,
        (const float*)hw, (const float*)hb, preds, xs, ys);
  else
    mlp_body<bf16>(xf,
        (const bf16*)w1, (const bf16*)b1, (const bf16*)g1, (const bf16*)be1, (const bf16*)pa1,
        (const bf16*)w2, (const bf16*)b2, (const bf16*)g2, (const bf16*)be2, (const bf16*)pa2,
        (const bf16*)w3, (const bf16*)b3, (const bf16*)g3, (const bf16*)be3, (const bf16*)pa3,
        (const bf16*)hw, (const bf16*)hb, preds, xs, ys);
}

// ---------------------------------------------------------------------------
extern "C" void kernel_launch(void* const* d_in, const int* in_sizes, int n_in,
                              void* d_out, int out_size, void* d_ws, size_t ws_size,
                              hipStream_t stream) {
  const int* behavior_ids = (const int*)d_in[0];
  const int* candidate_id = (const int*)d_in[1];
  const int* candidate_cat = (const int*)d_in[2];
  // float-family tensors passed as void*, dtype resolved on device
  const void* dense = d_in[3];
  const void* item_emb = d_in[4];
  const void* cat_emb = d_in[5];
  const void* gru_wih = d_in[6];
  const void* gru_whh = d_in[7];
  const void* gru_bih = d_in[8];
  const void* gru_bhh = d_in[9];
  const void* aux_w1 = d_in[10];
  const void* aux_b1 = d_in[11];
  const void* aux_w2 = d_in[12];
  const void* aux_b2 = d_in[13];
  const void* att_w1 = d_in[14];
  const void* att_b1 = d_in[15];
  const void* att_a = d_in[16];
  const void* att_w2 = d_in[17];
  const void* att_b2 = d_in[18];
  const void* wz = d_in[19];
  const void* bz = d_in[20];
  const void* wr = d_in[21];
  const void* br = d_in[22];
  const void* wh = d_in[23];
  const void* bh = d_in[24];
  const void* dp_w = d_in[25];
  const void* dp_b = d_in[26];
  const void* m_w1 = d_in[27];
  const void* m_b1 = d_in[28];
  const void* ln_g1 = d_in[29];   // ones(256) -> dtype discriminator
  const void* ln_b1 = d_in[30];
  const void* pa1 = d_in[31];
  const void* m_w2 = d_in[32];
  const void* m_b2 = d_in[33];
  const void* ln_g2 = d_in[34];
  const void* ln_b2 = d_in[35];
  const void* pa2 = d_in[36];
  const void* m_w3 = d_in[37];
  const void* m_b3 = d_in[38];
  const void* ln_g3 = d_in[39];
  const void* ln_b3 = d_in[40];
  const void* pa3 = d_in[41];
  const void* heads_w = d_in[42];
  const void* heads_b = d_in[43];
  (void)in_sizes; (void)n_in; (void)out_size; (void)ws_size;

  const unsigned* disc = (const unsigned*)ln_g1;

  char* ws = (char*)d_ws;
  bf16* HS = (bf16*)(ws);                        // (B,T,128) bf16   52,428,800 B
  float* SC = (float*)(ws + 52428800L);          // (B,T) fp32          819,200 B
  bf16* CAND = (bf16*)(ws + 53248000L);          // (B,128) bf16        262,144 B
  bf16* XF = (bf16*)(ws + 53510144L);            // (B,352) bf16        720,896 B
  float* OUT = (float*)d_out;                    // fp32 output

  k_prep<<<BATCH, 128, 0, stream>>>(disc, candidate_id, candidate_cat, dense, item_emb,
                                    cat_emb, dp_w, dp_b, CAND, XF);
  k_gru<<<64, 512, 0, stream>>>(disc, behavior_ids, item_emb, gru_wih, gru_whh,
                                gru_bih, gru_bhh, HS);
  k_aux<<<dim3(4, BATCH), 256, 0, stream>>>(disc, HS, aux_w1, aux_b1, aux_w2, aux_b2, OUT + 3072);
  k_att<<<dim3(4, BATCH), 256, 0, stream>>>(disc, HS, CAND, att_w1, att_b1, att_a, att_w2, att_b2, SC);
  k_softmax<<<BATCH, 256, 0, stream>>>(SC);
  k_augru<<<64, 512, 0, stream>>>(disc, HS, SC, wz, wr, wh, bz, br, bh, XF);
  k_mlp<<<256, 256, 0, stream>>>(disc, XF,
      m_w1, m_b1, ln_g1, ln_b1, pa1,
      m_w2, m_b2, ln_g2, ln_b2, pa2,
      m_w3, m_b3, ln_g3, ln_b3, pa3,
      heads_w, heads_b, OUT);
}

// Round 5
// 1066.606 us; speedup vs baseline: 1.1324x; 1.1324x over previous
//
#include <hip/hip_runtime.h>

// ---------------------------------------------------------------------------
// DIEN forward on MI355X (gfx950).  B=1024, T=200, E=128, H=128.
// Inputs fp32 (runtime-dispatched vs bf16 via ln_g1 discriminator).
// Compute: bf16 MFMA + fp32 accum.  Output fp32.
// Scan kernels: gates evaluated in MFMA C-layout registers (no LDS round
// trip); h kept fp32 in registers; double-buffered LDS tiles; GRU 1
// barrier/step, AUGRU 2 barriers/step.
// d_out (fp32): [0,3072) preds (B,3); [3072,3072+B*199) aux.
// ---------------------------------------------------------------------------

typedef __bf16 bf16;
typedef float f32x4 __attribute__((ext_vector_type(4)));
typedef __bf16 bf16x8 __attribute__((ext_vector_type(8)));
typedef __bf16 bf16x4 __attribute__((ext_vector_type(4)));

#define MFMA16(a, b, c) __builtin_amdgcn_mfma_f32_16x16x32_bf16((a), (b), (c), 0, 0, 0)

#define BATCH 1024
#define SEQT 200
#define F32_ONE 0x3F800000u

__device__ __forceinline__ float sigm(float x) { return 1.0f / (1.0f + __expf(-x)); }
__device__ __forceinline__ float tanh_fast(float x) {
  float ax = fabsf(x);
  float e = __expf(2.0f * ax);
  float t = 1.0f - 2.0f / (e + 1.0f);
  return copysignf(t, x);
}

// ---- dtype-generic loads ---------------------------------------------------
template <typename DT> __device__ __forceinline__ float ldf(const DT* p, long i);
template <> __device__ __forceinline__ float ldf<bf16>(const bf16* p, long i) { return (float)p[i]; }
template <> __device__ __forceinline__ float ldf<float>(const float* p, long i) { return p[i]; }

template <typename DT> __device__ __forceinline__ bf16x8 ld8(const DT* p, long i);
template <> __device__ __forceinline__ bf16x8 ld8<bf16>(const bf16* p, long i) {
  return *(const bf16x8*)(p + i);
}
template <> __device__ __forceinline__ bf16x8 ld8<float>(const float* p, long i) {
  f32x4 a = *(const f32x4*)(p + i);
  f32x4 b = *(const f32x4*)(p + i + 4);
  bf16x8 r;
  r[0] = (bf16)a[0]; r[1] = (bf16)a[1]; r[2] = (bf16)a[2]; r[3] = (bf16)a[3];
  r[4] = (bf16)b[0]; r[5] = (bf16)b[1]; r[6] = (bf16)b[2]; r[7] = (bf16)b[3];
  return r;
}

// ---------------------------------------------------------------------------
// prep: candidate gather, category gather, dense projection -> xfinal tail
// ---------------------------------------------------------------------------
template <typename DT>
__device__ __forceinline__ void prep_body(
    const int* __restrict__ cid, const int* __restrict__ ccat,
    const DT* __restrict__ dense, const DT* __restrict__ item_emb,
    const DT* __restrict__ cat_emb, const DT* __restrict__ dp_w,
    const DT* __restrict__ dp_b, bf16* __restrict__ candbuf, bf16* __restrict__ xf) {
  const int b = blockIdx.x;
  const int t = threadIdx.x;
  bf16 v = (bf16)ldf(item_emb, (long)cid[b] * 128 + t);
  candbuf[b * 128 + t] = v;
  xf[(long)b * 352 + 128 + t] = v;
  if (t < 64) xf[(long)b * 352 + 256 + t] = (bf16)ldf(cat_emb, (long)ccat[b] * 64 + t);
  if (t < 32) {
    float s = ldf(dp_b, t);
    for (int k = 0; k < 5; k++) s += ldf(dense, b * 5 + k) * ldf(dp_w, t * 5 + k);
    xf[(long)b * 352 + 320 + t] = (bf16)s;
  }
}
__global__ __launch_bounds__(128) void k_prep(
    const unsigned* __restrict__ disc, const int* cid, const int* ccat,
    const void* dense, const void* item_emb, const void* cat_emb,
    const void* dp_w, const void* dp_b, bf16* candbuf, bf16* xf) {
  if (*disc == F32_ONE)
    prep_body<float>(cid, ccat, (const float*)dense, (const float*)item_emb,
                     (const float*)cat_emb, (const float*)dp_w, (const float*)dp_b, candbuf, xf);
  else
    prep_body<bf16>(cid, ccat, (const bf16*)dense, (const bf16*)item_emb,
                    (const bf16*)cat_emb, (const bf16*)dp_w, (const bf16*)dp_b, candbuf, xf);
}

// ---------------------------------------------------------------------------
// GRU scan: gates in C-layout registers, 1 barrier/step.
// 16 batch rows/block, 512 threads (8 waves); wave w owns out cols 16w..16w+15.
// hA/xL double-buffered.  hs written coalesced from previous step's hA.
// ---------------------------------------------------------------------------
template <typename DT>
__device__ __forceinline__ void gru_body(
    const int* __restrict__ ids, const DT* __restrict__ item_emb,
    const DT* __restrict__ wih, const DT* __restrict__ whh,
    const DT* __restrict__ bih, const DT* __restrict__ bhh, bf16* __restrict__ hs,
    bf16 (*xL)[16][136], bf16 (*hA)[16][136]) {
  const int b0 = blockIdx.x * 16;
  const int tid = threadIdx.x;
  const int w = tid >> 6, lane = tid & 63, l15 = lane & 15, quad = lane >> 4;
  const int nc = w * 16 + l15;

  for (int i = tid; i < 2 * 16 * 136; i += 512) ((bf16*)hA)[i] = (bf16)0.0f;

  bf16x8 wir[4], wiz[4], win_[4], whr[4], whz[4], whn[4];
#pragma unroll
  for (int k = 0; k < 4; k++) {
    const long off = k * 32 + quad * 8;
    wir[k] = ld8(wih, (long)nc * 128 + off);
    wiz[k] = ld8(wih, (long)(128 + nc) * 128 + off);
    win_[k] = ld8(wih, (long)(256 + nc) * 128 + off);
    whr[k] = ld8(whh, (long)nc * 128 + off);
    whz[k] = ld8(whh, (long)(128 + nc) * 128 + off);
    whn[k] = ld8(whh, (long)(256 + nc) * 128 + off);
  }
  const float br_s = ldf(bih, nc) + ldf(bhh, nc);
  const float bz_s = ldf(bih, 128 + nc) + ldf(bhh, 128 + nc);
  const float bxn_s = ldf(bih, 256 + nc);
  const float bhn_s = ldf(bhh, 256 + nc);

  const int row = tid >> 4, ch = tid & 15;
  long ib = 0; int idn = 0; bf16x8 pf;
  if (tid < 256) {
    ib = (long)(b0 + row) * SEQT;
    *(bf16x8*)&xL[0][row][ch * 8] = ld8(item_emb, (long)ids[ib] * 128 + ch * 8);
    idn = ids[ib + 1];
  }
  float hreg[4] = {0.f, 0.f, 0.f, 0.f};
  const f32x4 z4 = {0.f, 0.f, 0.f, 0.f};
  __syncthreads();

  for (int t = 0; t < SEQT; t++) {
    const int cur = t & 1, nxt = cur ^ 1;
    // prefetch x_{t+1}
    if (tid < 256) {
      if (t + 1 < SEQT) pf = ld8(item_emb, (long)idn * 128 + ch * 8);
      if (t + 2 < SEQT) idn = ids[ib + t + 2];
    }
    // coalesced hs write of previous step's result (hA[cur] holds hs[:,t-1])
    if (t && tid < 256) {
      bf16x8 hv8 = *(const bf16x8*)&hA[cur][row][ch * 8];
      *(bf16x8*)(hs + ((long)(b0 + row) * SEQT + (t - 1)) * 128 + ch * 8) = hv8;
    }
    // MFMA: 6 independent 4-chains
    bf16x8 af[4], xfr[4];
#pragma unroll
    for (int k = 0; k < 4; k++) {
      af[k] = *(const bf16x8*)&hA[cur][l15][k * 32 + quad * 8];
      xfr[k] = *(const bf16x8*)&xL[cur][l15][k * 32 + quad * 8];
    }
    f32x4 arx = z4, arh = z4, azx = z4, azh = z4, axn = z4, ahn = z4;
#pragma unroll
    for (int k = 0; k < 4; k++) {
      arx = MFMA16(xfr[k], wir[k], arx);
      arh = MFMA16(af[k], whr[k], arh);
      azx = MFMA16(xfr[k], wiz[k], azx);
      azh = MFMA16(af[k], whz[k], azh);
      axn = MFMA16(xfr[k], win_[k], axn);
      ahn = MFMA16(af[k], whn[k], ahn);
    }
    // gates in registers (C-layout: row=quad*4+r, col=nc)
#pragma unroll
    for (int r = 0; r < 4; r++) {
      float r_ = sigm(arx[r] + arh[r] + br_s);
      float z_ = sigm(azx[r] + azh[r] + bz_s);
      float n_ = tanh_fast(axn[r] + bxn_s + r_ * (ahn[r] + bhn_s));
      float hnew = (1.0f - z_) * n_ + z_ * hreg[r];
      hreg[r] = hnew;
      hA[nxt][quad * 4 + r][nc] = (bf16)hnew;
    }
    // publish x_{t+1}
    if (tid < 256 && t + 1 < SEQT) *(bf16x8*)&xL[nxt][row][ch * 8] = pf;
    __syncthreads();
  }
  // final hs[:,199] from hA[SEQT&1]
  if (tid < 256) {
    bf16x8 hv8 = *(const bf16x8*)&hA[SEQT & 1][row][ch * 8];
    *(bf16x8*)(hs + ((long)(b0 + row) * SEQT + (SEQT - 1)) * 128 + ch * 8) = hv8;
  }
}
__global__ __launch_bounds__(512) void k_gru(
    const unsigned* __restrict__ disc, const int* ids, const void* item_emb,
    const void* wih, const void* whh, const void* bih, const void* bhh, bf16* hs) {
  __shared__ bf16 xL[2][16][136];
  __shared__ bf16 hA[2][16][136];
  if (*disc == F32_ONE)
    gru_body<float>(ids, (const float*)item_emb, (const float*)wih, (const float*)whh,
                    (const float*)bih, (const float*)bhh, hs, xL, hA);
  else
    gru_body<bf16>(ids, (const bf16*)item_emb, (const bf16*)wih, (const bf16*)whh,
                   (const bf16*)bih, (const bf16*)bhh, hs, xL, hA);
}

// ---------------------------------------------------------------------------
// aux head: relu(hs[:, :199] @ w1^T + b1) @ w2^T + b2 (fused N=1 reduction).
// ---------------------------------------------------------------------------
template <typename DT>
__device__ __forceinline__ void aux_body(
    const bf16* __restrict__ hs, const DT* __restrict__ w1, const DT* __restrict__ b1v,
    const DT* __restrict__ w2v, const DT* __restrict__ b2v, float* __restrict__ outaux,
    bf16 (*As)[136], bf16 (*Ws)[136]) {
  const int b = blockIdx.y;
  const int t0 = blockIdx.x * 64;
  const int tid = threadIdx.x;
#pragma unroll
  for (int j = 0; j < 4; j++) {
    int ci = j * 256 + tid;
    int row = ci >> 4, k8 = (ci & 15) * 8;
    int t = t0 + row; int tc = t < 199 ? t : 198;
    *(bf16x8*)&As[row][k8] = *(const bf16x8*)(hs + ((long)b * SEQT + tc) * 128 + k8);
  }
#pragma unroll
  for (int j = 0; j < 8; j++) {
    int ci = j * 256 + tid;
    int row = ci >> 4, k8 = (ci & 15) * 8;
    *(bf16x8*)&Ws[row][k8] = ld8(w1, (long)row * 128 + k8);
  }
  __syncthreads();
  const int w = tid >> 6, lane = tid & 63, l15 = lane & 15, quad = lane >> 4;
  bf16x8 af[4];
#pragma unroll
  for (int k = 0; k < 4; k++) af[k] = *(const bf16x8*)&As[w * 16 + l15][k * 32 + quad * 8];
  const f32x4 z4 = {0.f, 0.f, 0.f, 0.f};
  float part[4] = {0.f, 0.f, 0.f, 0.f};
#pragma unroll
  for (int nt = 0; nt < 8; nt++) {
    f32x4 acc = z4;
#pragma unroll
    for (int k = 0; k < 4; k++) {
      bf16x8 bfr = *(const bf16x8*)&Ws[nt * 16 + l15][k * 32 + quad * 8];
      acc = MFMA16(af[k], bfr, acc);
    }
    int n = nt * 16 + l15;
    float b1f = ldf(b1v, n), w2f = ldf(w2v, n);
#pragma unroll
    for (int r = 0; r < 4; r++) {
      float y = acc[r] + b1f;
      part[r] += (y > 0.f ? y : 0.f) * w2f;
    }
  }
#pragma unroll
  for (int m = 1; m < 16; m <<= 1)
#pragma unroll
    for (int r = 0; r < 4; r++) part[r] += __shfl_xor(part[r], m, 64);
  if (l15 == 0) {
    float b2 = ldf(b2v, 0);
#pragma unroll
    for (int r = 0; r < 4; r++) {
      int t = t0 + w * 16 + quad * 4 + r;
      if (t < 199) outaux[(long)b * 199 + t] = part[r] + b2;
    }
  }
}
__global__ __launch_bounds__(256) void k_aux(
    const unsigned* __restrict__ disc, const bf16* hs, const void* w1, const void* b1v,
    const void* w2v, const void* b2v, float* outaux) {
  __shared__ bf16 As[64][136];
  __shared__ bf16 Ws[128][136];
  if (*disc == F32_ONE)
    aux_body<float>(hs, (const float*)w1, (const float*)b1v, (const float*)w2v,
                    (const float*)b2v, outaux, As, Ws);
  else
    aux_body<bf16>(hs, (const bf16*)w1, (const bf16*)b1v, (const bf16*)w2v,
                   (const bf16*)b2v, outaux, As, Ws);
}

// ---------------------------------------------------------------------------
// attention scores: prelu([hs,cand,hs*cand] @ w1^T + b1, a) @ w2^T + b2.
// ---------------------------------------------------------------------------
template <typename DT>
__device__ __forceinline__ void att_body(
    const bf16* __restrict__ hs, const bf16* __restrict__ cand,
    const DT* __restrict__ w1, const DT* __restrict__ b1v, const DT* __restrict__ a_s,
    const DT* __restrict__ w2v, const DT* __restrict__ b2v, float* __restrict__ scores,
    bf16 (*As)[392]) {
  const int b = blockIdx.y;
  const int t0 = blockIdx.x * 64;
  const int tid = threadIdx.x;
#pragma unroll
  for (int j = 0; j < 12; j++) {
    int ci = j * 256 + tid;
    int row = ci / 48;
    int k8 = (ci % 48) * 8;
    int t = t0 + row; int tc = t < SEQT ? t : SEQT - 1;
    const bf16* hrow = hs + ((long)b * SEQT + tc) * 128;
    bf16x8 v;
    if (k8 < 128) v = *(const bf16x8*)(hrow + k8);
    else if (k8 < 256) v = *(const bf16x8*)(cand + b * 128 + (k8 - 128));
    else {
      bf16x8 hv = *(const bf16x8*)(hrow + (k8 - 256));
      bf16x8 cv = *(const bf16x8*)(cand + b * 128 + (k8 - 256));
#pragma unroll
      for (int q = 0; q < 8; q++) v[q] = (bf16)((float)hv[q] * (float)cv[q]);
    }
    *(bf16x8*)&As[row][k8] = v;
  }
  __syncthreads();
  const int w = tid >> 6, lane = tid & 63, l15 = lane & 15, quad = lane >> 4;
  const f32x4 z4 = {0.f, 0.f, 0.f, 0.f};
  f32x4 acc[4] = {z4, z4, z4, z4};
  for (int k = 0; k < 12; k++) {
    bf16x8 af = *(const bf16x8*)&As[w * 16 + l15][k * 32 + quad * 8];
#pragma unroll
    for (int nt = 0; nt < 4; nt++) {
      bf16x8 bfr = ld8(w1, (long)(nt * 16 + l15) * 384 + k * 32 + quad * 8);
      acc[nt] = MFMA16(af, bfr, acc[nt]);
    }
  }
  float aP = ldf(a_s, 0);
  float part[4] = {0.f, 0.f, 0.f, 0.f};
#pragma unroll
  for (int nt = 0; nt < 4; nt++) {
    int n = nt * 16 + l15;
    float b1f = ldf(b1v, n), w2f = ldf(w2v, n);
#pragma unroll
    for (int r = 0; r < 4; r++) {
      float y = acc[nt][r] + b1f;
      y = (y >= 0.f) ? y : aP * y;
      part[r] += y * w2f;
    }
  }
#pragma unroll
  for (int m = 1; m < 16; m <<= 1)
#pragma unroll
    for (int r = 0; r < 4; r++) part[r] += __shfl_xor(part[r], m, 64);
  if (l15 == 0) {
    float b2 = ldf(b2v, 0);
#pragma unroll
    for (int r = 0; r < 4; r++) {
      int t = t0 + w * 16 + quad * 4 + r;
      if (t < SEQT) scores[(long)b * SEQT + t] = part[r] + b2;
    }
  }
}
__global__ __launch_bounds__(256) void k_att(
    const unsigned* __restrict__ disc, const bf16* hs, const bf16* cand,
    const void* w1, const void* b1v, const void* a_s,
    const void* w2v, const void* b2v, float* scores) {
  __shared__ bf16 As[64][392];
  if (*disc == F32_ONE)
    att_body<float>(hs, cand, (const float*)w1, (const float*)b1v, (const float*)a_s,
                    (const float*)w2v, (const float*)b2v, scores, As);
  else
    att_body<bf16>(hs, cand, (const bf16*)w1, (const bf16*)b1v, (const bf16*)a_s,
                   (const bf16*)w2v, (const bf16*)b2v, scores, As);
}

// ---------------------------------------------------------------------------
// softmax over T=200, in place on fp32 scores.
// ---------------------------------------------------------------------------
__global__ __launch_bounds__(256) void k_softmax(float* __restrict__ sc) {
  const int b = blockIdx.x, tid = threadIdx.x;
  __shared__ float red[256];
  float v = (tid < SEQT) ? sc[(long)b * SEQT + tid] : -1e30f;
  red[tid] = v; __syncthreads();
  for (int s = 128; s > 0; s >>= 1) { if (tid < s) red[tid] = fmaxf(red[tid], red[tid + s]); __syncthreads(); }
  float mx = red[0]; __syncthreads();
  float e = (tid < SEQT) ? __expf(v - mx) : 0.f;
  red[tid] = e; __syncthreads();
  for (int s = 128; s > 0; s >>= 1) { if (tid < s) red[tid] += red[tid + s]; __syncthreads(); }
  float inv = 1.0f / red[0];
  if (tid < SEQT) sc[(long)b * SEQT + tid] = e * inv;
}

// ---------------------------------------------------------------------------
// AUGRU scan: gates in C-layout registers, 2 barriers/step.
// att weights preloaded to LDS.  h fp32 in registers.
// ---------------------------------------------------------------------------
template <typename DT>
__device__ __forceinline__ void augru_body(
    const bf16* __restrict__ hsrc, const float* __restrict__ att,
    const DT* __restrict__ wz, const DT* __restrict__ wr, const DT* __restrict__ wh,
    const DT* __restrict__ bzv, const DT* __restrict__ brv, const DT* __restrict__ bhv,
    bf16* __restrict__ xf_out,
    bf16 (*xA)[16][136], bf16 (*hA)[16][136], bf16 (*rhA)[136], float (*attL)[201]) {
  const int b0 = blockIdx.x * 16;
  const int tid = threadIdx.x;
  const int w = tid >> 6, lane = tid & 63, l15 = lane & 15, quad = lane >> 4;
  const int nc = w * 16 + l15;

  for (int i = tid; i < 2 * 16 * 136; i += 512) ((bf16*)hA)[i] = (bf16)0.0f;
  for (int i = tid; i < 16 * SEQT; i += 512) {
    int r = i / SEQT, c = i - r * SEQT;
    attL[r][c] = att[(long)(b0 + r) * SEQT + c];
  }

  bf16x8 wzx[4], wzh[4], wrx[4], wrh[4], whx[4], whh_[4];
#pragma unroll
  for (int k = 0; k < 4; k++) {
    const long off = k * 32 + quad * 8;
    wzx[k] = ld8(wz, (long)nc * 256 + off);
    wzh[k] = ld8(wz, (long)nc * 256 + 128 + off);
    wrx[k] = ld8(wr, (long)nc * 256 + off);
    wrh[k] = ld8(wr, (long)nc * 256 + 128 + off);
    whx[k] = ld8(wh, (long)nc * 256 + off);
    whh_[k] = ld8(wh, (long)nc * 256 + 128 + off);
  }
  const float bz_s = ldf(bzv, nc);
  const float br_s = ldf(brv, nc);
  const float bh_s = ldf(bhv, nc);

  const int row = tid >> 4, ch = tid & 15;
  bf16x8 pf;
  if (tid < 256)
    *(bf16x8*)&xA[0][row][ch * 8] =
        *(const bf16x8*)(hsrc + ((long)(b0 + row) * SEQT) * 128 + ch * 8);

  float hreg[4] = {0.f, 0.f, 0.f, 0.f};
  const f32x4 z4 = {0.f, 0.f, 0.f, 0.f};
  __syncthreads();

  for (int t = 0; t < SEQT; t++) {
    const int cur = t & 1, nxt = cur ^ 1;
    if (tid < 256 && t + 1 < SEQT)
      pf = *(const bf16x8*)(hsrc + ((long)(b0 + row) * SEQT + t + 1) * 128 + ch * 8);

    // ---- phase A: z, r, xh (5 independent 4-chains)
    bf16x8 af[4], xfr[4];
#pragma unroll
    for (int k = 0; k < 4; k++) {
      af[k] = *(const bf16x8*)&hA[cur][l15][k * 32 + quad * 8];
      xfr[k] = *(const bf16x8*)&xA[cur][l15][k * 32 + quad * 8];
    }
    f32x4 azx = z4, azh = z4, arx = z4, arh = z4, axh = z4;
#pragma unroll
    for (int k = 0; k < 4; k++) {
      azx = MFMA16(xfr[k], wzx[k], azx);
      azh = MFMA16(af[k], wzh[k], azh);
      arx = MFMA16(xfr[k], wrx[k], arx);
      arh = MFMA16(af[k], wrh[k], arh);
      axh = MFMA16(xfr[k], whx[k], axh);
    }
    float zp[4];
#pragma unroll
    for (int r = 0; r < 4; r++) {
      float a_ = attL[quad * 4 + r][t];
      float z_ = sigm(azx[r] + azh[r] + bz_s);
      float r_ = sigm(arx[r] + arh[r] + br_s);
      zp[r] = a_ * z_;
      rhA[quad * 4 + r][nc] = (bf16)(r_ * hreg[r]);
    }
    __syncthreads();

    // ---- phase C: hh = (r*h) @ whh^T
    bf16x8 rf[4];
#pragma unroll
    for (int k = 0; k < 4; k++) rf[k] = *(const bf16x8*)&rhA[l15][k * 32 + quad * 8];
    f32x4 ahh = z4;
#pragma unroll
    for (int k = 0; k < 4; k++) ahh = MFMA16(rf[k], whh_[k], ahh);

    // ---- phase D: gated update in registers
#pragma unroll
    for (int r = 0; r < 4; r++) {
      float ht = tanh_fast(axh[r] + bh_s + ahh[r]);
      float hnew = (1.f - zp[r]) * hreg[r] + zp[r] * ht;
      hreg[r] = hnew;
      hA[nxt][quad * 4 + r][nc] = (bf16)hnew;
    }
    if (t == SEQT - 1) {
#pragma unroll
      for (int r = 0; r < 4; r++)
        xf_out[(long)(b0 + quad * 4 + r) * 352 + nc] = (bf16)hreg[r];
    }
    if (tid < 256 && t + 1 < SEQT) *(bf16x8*)&xA[nxt][row][ch * 8] = pf;
    __syncthreads();
  }
}
__global__ __launch_bounds__(512) void k_augru(
    const unsigned* __restrict__ disc, const bf16* hsrc, const float* att,
    const void* wz, const void* wr, const void* wh,
    const void* bzv, const void* brv, const void* bhv, bf16* xf_out) {
  __shared__ bf16 xA[2][16][136];
  __shared__ bf16 hA[2][16][136];
  __shared__ bf16 rhA[16][136];
  __shared__ float attL[16][201];
  if (*disc == F32_ONE)
    augru_body<float>(hsrc, att, (const float*)wz, (const float*)wr, (const float*)wh,
                      (const float*)bzv, (const float*)brv, (const float*)bhv, xf_out,
                      xA, hA, rhA, attL);
  else
    augru_body<bf16>(hsrc, att, (const bf16*)wz, (const bf16*)wr, (const bf16*)wh,
                     (const bf16*)bzv, (const bf16*)brv, (const bf16*)bhv, xf_out,
                     xA, hA, rhA, attL);
}

// ---------------------------------------------------------------------------
// final MLP: 352->256->128->64 (LN+prelu each) -> 3 heads (sigmoid, fp32 out).
// ---------------------------------------------------------------------------
template <typename DT>
__device__ __forceinline__ void mlp_body(
    const bf16* __restrict__ xf,
    const DT* __restrict__ w1, const DT* __restrict__ b1, const DT* __restrict__ g1, const DT* __restrict__ be1, const DT* __restrict__ pa1,
    const DT* __restrict__ w2, const DT* __restrict__ b2, const DT* __restrict__ g2, const DT* __restrict__ be2, const DT* __restrict__ pa2,
    const DT* __restrict__ w3, const DT* __restrict__ b3, const DT* __restrict__ g3, const DT* __restrict__ be3, const DT* __restrict__ pa3,
    const DT* __restrict__ hw, const DT* __restrict__ hb, float* __restrict__ preds,
    float (*xs)[352], float (*ys)[256]) {
  const int tid = threadIdx.x, w = tid >> 6, lane = tid & 63;
  const int b = blockIdx.x * 4 + w;
  for (int i = lane; i < 352; i += 64) xs[w][i] = (float)xf[(long)b * 352 + i];
  __syncthreads();
  float acc1[4];
#pragma unroll
  for (int oi = 0; oi < 4; oi++) {
    int o = lane + 64 * oi;
    float s = ldf(b1, o);
    for (int k = 0; k < 352; k += 8) {
      bf16x8 wv = ld8(w1, (long)o * 352 + k);
#pragma unroll
      for (int j = 0; j < 8; j++) s += xs[w][k + j] * (float)wv[j];
    }
    acc1[oi] = s;
  }
  float sm = acc1[0] + acc1[1] + acc1[2] + acc1[3];
#pragma unroll
  for (int m = 1; m < 64; m <<= 1) sm += __shfl_xor(sm, m, 64);
  float mean = sm * (1.0f / 256.0f);
  float vs = 0.f;
#pragma unroll
  for (int oi = 0; oi < 4; oi++) { float d = acc1[oi] - mean; vs += d * d; }
#pragma unroll
  for (int m = 1; m < 64; m <<= 1) vs += __shfl_xor(vs, m, 64);
  float rstd = rsqrtf(vs * (1.0f / 256.0f) + 1e-5f);
  float a1 = ldf(pa1, 0);
#pragma unroll
  for (int oi = 0; oi < 4; oi++) {
    int o = lane + 64 * oi;
    float y = (acc1[oi] - mean) * rstd * ldf(g1, o) + ldf(be1, o);
    ys[w][o] = (y >= 0.f) ? y : a1 * y;
  }
  __syncthreads();
  float acc2[2];
#pragma unroll
  for (int oi = 0; oi < 2; oi++) {
    int o = lane + 64 * oi;
    float s = ldf(b2, o);
    for (int k = 0; k < 256; k += 8) {
      bf16x8 wv = ld8(w2, (long)o * 256 + k);
#pragma unroll
      for (int j = 0; j < 8; j++) s += ys[w][k + j] * (float)wv[j];
    }
    acc2[oi] = s;
  }
  sm = acc2[0] + acc2[1];
#pragma unroll
  for (int m = 1; m < 64; m <<= 1) sm += __shfl_xor(sm, m, 64);
  mean = sm * (1.0f / 128.0f);
  vs = 0.f;
#pragma unroll
  for (int oi = 0; oi < 2; oi++) { float d = acc2[oi] - mean; vs += d * d; }
#pragma unroll
  for (int m = 1; m < 64; m <<= 1) vs += __shfl_xor(vs, m, 64);
  rstd = rsqrtf(vs * (1.0f / 128.0f) + 1e-5f);
  float a2 = ldf(pa2, 0);
  __syncthreads();
#pragma unroll
  for (int oi = 0; oi < 2; oi++) {
    int o = lane + 64 * oi;
    float y = (acc2[oi] - mean) * rstd * ldf(g2, o) + ldf(be2, o);
    xs[w][o] = (y >= 0.f) ? y : a2 * y;
  }
  __syncthreads();
  float s3 = ldf(b3, lane);
  for (int k = 0; k < 128; k += 8) {
    bf16x8 wv = ld8(w3, (long)lane * 128 + k);
#pragma unroll
    for (int j = 0; j < 8; j++) s3 += xs[w][k + j] * (float)wv[j];
  }
  sm = s3;
#pragma unroll
  for (int m = 1; m < 64; m <<= 1) sm += __shfl_xor(sm, m, 64);
  mean = sm * (1.0f / 64.0f);
  float d3 = s3 - mean;
  vs = d3 * d3;
#pragma unroll
  for (int m = 1; m < 64; m <<= 1) vs += __shfl_xor(vs, m, 64);
  rstd = rsqrtf(vs * (1.0f / 64.0f) + 1e-5f);
  float a3 = ldf(pa3, 0);
  float y3 = d3 * rstd * ldf(g3, lane) + ldf(be3, lane);
  y3 = (y3 >= 0.f) ? y3 : a3 * y3;
  ys[w][lane] = y3;
  __syncthreads();
  if (lane < 3) {
    float s = ldf(hb, lane);
    for (int k = 0; k < 64; k++) s += ys[w][k] * ldf(hw, lane * 64 + k);
    preds[(long)b * 3 + lane] = sigm(s);
  }
}
__global__ __launch_bounds__(256) void k_mlp(
    const unsigned* __restrict__ disc, const bf16* xf,
    const void* w1, const void* b1, const void* g1, const void* be1, const void* pa1,
    const void* w2, const void* b2, const void* g2, const void* be2, const void* pa2,
    const void* w3, const void* b3, const void* g3, const void* be3, const void* pa3,
    const void* hw, const void* hb, float* preds) {
  __shared__ float xs[4][352];
  __shared__ float ys[4][256];
  if (*disc == F32_ONE)
    mlp_body<float>(xf,
        (const float*)w1, (const float*)b1, (const float*)g1, (const float*)be1, (const float*)pa1,
        (const float*)w2, (const float*)b2, (const float*)g2, (const float*)be2, (const float*)pa2,
        (const float*)w3, (const float*)b3, (const float*)g3, (const float*)be3, (const float*)pa3,
        (const float*)hw, (const float*)hb, preds, xs, ys);
  else
    mlp_body<bf16>(xf,
        (const bf16*)w1, (const bf16*)b1, (const bf16*)g1, (const bf16*)be1, (const bf16*)pa1,
        (const bf16*)w2, (const bf16*)b2, (const bf16*)g2, (const bf16*)be2, (const bf16*)pa2,
        (const bf16*)w3, (const bf16*)b3, (const bf16*)g3, (const bf16*)be3, (const bf16*)pa3,
        (const bf16*)hw, (const bf16*)hb, preds, xs, ys);
}

// ---------------------------------------------------------------------------
extern "C" void kernel_launch(void* const* d_in, const int* in_sizes, int n_in,
                              void* d_out, int out_size, void* d_ws, size_t ws_size,
                              hipStream_t stream) {
  const int* behavior_ids = (const int*)d_in[0];
  const int* candidate_id = (const int*)d_in[1];
  const int* candidate_cat = (const int*)d_in[2];
  const void* dense = d_in[3];
  const void* item_emb = d_in[4];
  const void* cat_emb = d_in[5];
  const void* gru_wih = d_in[6];
  const void* gru_whh = d_in[7];
  const void* gru_bih = d_in[8];
  const void* gru_bhh = d_in[9];
  const void* aux_w1 = d_in[10];
  const void* aux_b1 = d_in[11];
  const void* aux_w2 = d_in[12];
  const void* aux_b2 = d_in[13];
  const void* att_w1 = d_in[14];
  const void* att_b1 = d_in[15];
  const void* att_a = d_in[16];
  const void* att_w2 = d_in[17];
  const void* att_b2 = d_in[18];
  const void* wz = d_in[19];
  const void* bz = d_in[20];
  const void* wr = d_in[21];
  const void* br = d_in[22];
  const void* wh = d_in[23];
  const void* bh = d_in[24];
  const void* dp_w = d_in[25];
  const void* dp_b = d_in[26];
  const void* m_w1 = d_in[27];
  const void* m_b1 = d_in[28];
  const void* ln_g1 = d_in[29];   // ones -> dtype discriminator
  const void* ln_b1 = d_in[30];
  const void* pa1 = d_in[31];
  const void* m_w2 = d_in[32];
  const void* m_b2 = d_in[33];
  const void* ln_g2 = d_in[34];
  const void* ln_b2 = d_in[35];
  const void* pa2 = d_in[36];
  const void* m_w3 = d_in[37];
  const void* m_b3 = d_in[38];
  const void* ln_g3 = d_in[39];
  const void* ln_b3 = d_in[40];
  const void* pa3 = d_in[41];
  const void* heads_w = d_in[42];
  const void* heads_b = d_in[43];
  (void)in_sizes; (void)n_in; (void)out_size; (void)ws_size;

  const unsigned* disc = (const unsigned*)ln_g1;

  char* ws = (char*)d_ws;
  bf16* HS = (bf16*)(ws);                        // (B,T,128) bf16   52,428,800 B
  float* SC = (float*)(ws + 52428800L);          // (B,T) fp32          819,200 B
  bf16* CAND = (bf16*)(ws + 53248000L);          // (B,128) bf16        262,144 B
  bf16* XF = (bf16*)(ws + 53510144L);            // (B,352) bf16        720,896 B
  float* OUT = (float*)d_out;                    // fp32 output

  k_prep<<<BATCH, 128, 0, stream>>>(disc, candidate_id, candidate_cat, dense, item_emb,
                                    cat_emb, dp_w, dp_b, CAND, XF);
  k_gru<<<64, 512, 0, stream>>>(disc, behavior_ids, item_emb, gru_wih, gru_whh,
                                gru_bih, gru_bhh, HS);
  k_aux<<<dim3(4, BATCH), 256, 0, stream>>>(disc, HS, aux_w1, aux_b1, aux_w2, aux_b2, OUT + 3072);
  k_att<<<dim3(4, BATCH), 256, 0, stream>>>(disc, HS, CAND, att_w1, att_b1, att_a, att_w2, att_b2, SC);
  k_softmax<<<BATCH, 256, 0, stream>>>(SC);
  k_augru<<<64, 512, 0, stream>>>(disc, HS, SC, wz, wr, wh, bz, br, bh, XF);
  k_mlp<<<256, 256, 0, stream>>>(disc, XF,
      m_w1, m_b1, ln_g1, ln_b1, pa1,
      m_w2, m_b2, ln_g2, ln_b2, pa2,
      m_w3, m_b3, ln_g3, ln_b3, pa3,
      heads_w, heads_b, OUT);
}

// Round 6
// 959.019 us; speedup vs baseline: 1.2594x; 1.1122x over previous
//
#include <hip/hip_runtime.h>

// ---------------------------------------------------------------------------
// DIEN forward on MI355X (gfx950).  B=1024, T=200, E=128, H=128.
// Inputs fp32 (runtime-dispatched vs bf16 via ln_g1 discriminator).
// Compute: bf16 MFMA + fp32 accum.  Output fp32.
// Scans: lgkm-only barriers (global prefetches stay in flight), prefetch
// distance 2, gates in MFMA C-layout registers, h fp32 in registers.
// att/aux: weights staged once per block, 16 batch rows per block.
// d_out (fp32): [0,3072) preds (B,3); [3072,3072+B*199) aux.
// ---------------------------------------------------------------------------

typedef __bf16 bf16;
typedef float f32x4 __attribute__((ext_vector_type(4)));
typedef __bf16 bf16x8 __attribute__((ext_vector_type(8)));
typedef __bf16 bf16x4 __attribute__((ext_vector_type(4)));

#define MFMA16(a, b, c) __builtin_amdgcn_mfma_f32_16x16x32_bf16((a), (b), (c), 0, 0, 0)

#define BATCH 1024
#define SEQT 200
#define F32_ONE 0x3F800000u

__device__ __forceinline__ float sigm(float x) { return 1.0f / (1.0f + __expf(-x)); }
__device__ __forceinline__ float tanh_fast(float x) {
  float ax = fabsf(x);
  float e = __expf(2.0f * ax);
  float t = 1.0f - 2.0f / (e + 1.0f);
  return copysignf(t, x);
}

// lgkm-only barrier: does NOT drain vmcnt, so global prefetch loads / hs
// stores stay in flight across the step boundary. All cross-thread dataflow
// inside the scan loops is via LDS, so lgkmcnt(0) is sufficient.
__device__ __forceinline__ void bar_lgkm() {
  asm volatile("s_waitcnt lgkmcnt(0)\n\ts_barrier" ::: "memory");
}

// ---- dtype-generic loads ---------------------------------------------------
template <typename DT> __device__ __forceinline__ float ldf(const DT* p, long i);
template <> __device__ __forceinline__ float ldf<bf16>(const bf16* p, long i) { return (float)p[i]; }
template <> __device__ __forceinline__ float ldf<float>(const float* p, long i) { return p[i]; }

template <typename DT> __device__ __forceinline__ bf16x8 ld8(const DT* p, long i);
template <> __device__ __forceinline__ bf16x8 ld8<bf16>(const bf16* p, long i) {
  return *(const bf16x8*)(p + i);
}
template <> __device__ __forceinline__ bf16x8 ld8<float>(const float* p, long i) {
  f32x4 a = *(const f32x4*)(p + i);
  f32x4 b = *(const f32x4*)(p + i + 4);
  bf16x8 r;
  r[0] = (bf16)a[0]; r[1] = (bf16)a[1]; r[2] = (bf16)a[2]; r[3] = (bf16)a[3];
  r[4] = (bf16)b[0]; r[5] = (bf16)b[1]; r[6] = (bf16)b[2]; r[7] = (bf16)b[3];
  return r;
}

// ---------------------------------------------------------------------------
// prep
// ---------------------------------------------------------------------------
template <typename DT>
__device__ __forceinline__ void prep_body(
    const int* __restrict__ cid, const int* __restrict__ ccat,
    const DT* __restrict__ dense, const DT* __restrict__ item_emb,
    const DT* __restrict__ cat_emb, const DT* __restrict__ dp_w,
    const DT* __restrict__ dp_b, bf16* __restrict__ candbuf, bf16* __restrict__ xf) {
  const int b = blockIdx.x;
  const int t = threadIdx.x;
  bf16 v = (bf16)ldf(item_emb, (long)cid[b] * 128 + t);
  candbuf[b * 128 + t] = v;
  xf[(long)b * 352 + 128 + t] = v;
  if (t < 64) xf[(long)b * 352 + 256 + t] = (bf16)ldf(cat_emb, (long)ccat[b] * 64 + t);
  if (t < 32) {
    float s = ldf(dp_b, t);
    for (int k = 0; k < 5; k++) s += ldf(dense, b * 5 + k) * ldf(dp_w, t * 5 + k);
    xf[(long)b * 352 + 320 + t] = (bf16)s;
  }
}
__global__ __launch_bounds__(128) void k_prep(
    const unsigned* __restrict__ disc, const int* cid, const int* ccat,
    const void* dense, const void* item_emb, const void* cat_emb,
    const void* dp_w, const void* dp_b, bf16* candbuf, bf16* xf) {
  if (*disc == F32_ONE)
    prep_body<float>(cid, ccat, (const float*)dense, (const float*)item_emb,
                     (const float*)cat_emb, (const float*)dp_w, (const float*)dp_b, candbuf, xf);
  else
    prep_body<bf16>(cid, ccat, (const bf16*)dense, (const bf16*)item_emb,
                    (const bf16*)cat_emb, (const bf16*)dp_w, (const bf16*)dp_b, candbuf, xf);
}

// ---------------------------------------------------------------------------
// GRU scan: 1 lgkm barrier/step, distance-2 prefetch, gates in registers.
// ---------------------------------------------------------------------------
template <typename DT>
__device__ __forceinline__ void gru_body(
    const int* __restrict__ ids, const DT* __restrict__ item_emb,
    const DT* __restrict__ wih, const DT* __restrict__ whh,
    const DT* __restrict__ bih, const DT* __restrict__ bhh, bf16* __restrict__ hs,
    bf16 (*xL)[16][136], bf16 (*hA)[16][136]) {
  const int b0 = blockIdx.x * 16;
  const int tid = threadIdx.x;
  const int w = tid >> 6, lane = tid & 63, l15 = lane & 15, quad = lane >> 4;
  const int nc = w * 16 + l15;

  for (int i = tid; i < 2 * 16 * 136; i += 512) ((bf16*)hA)[i] = (bf16)0.0f;

  bf16x8 wir[4], wiz[4], win_[4], whr[4], whz[4], whn[4];
#pragma unroll
  for (int k = 0; k < 4; k++) {
    const long off = k * 32 + quad * 8;
    wir[k] = ld8(wih, (long)nc * 128 + off);
    wiz[k] = ld8(wih, (long)(128 + nc) * 128 + off);
    win_[k] = ld8(wih, (long)(256 + nc) * 128 + off);
    whr[k] = ld8(whh, (long)nc * 128 + off);
    whz[k] = ld8(whh, (long)(128 + nc) * 128 + off);
    whn[k] = ld8(whh, (long)(256 + nc) * 128 + off);
  }
  const float br_s = ldf(bih, nc) + ldf(bhh, nc);
  const float bz_s = ldf(bih, 128 + nc) + ldf(bhh, 128 + nc);
  const float bxn_s = ldf(bih, 256 + nc);
  const float bhn_s = ldf(bhh, 256 + nc);

  const int row = tid >> 4, ch = tid & 15;
  long ib = 0;
  int idA = 0, idB = 0;
  bf16x8 pf0, pf1;
  if (tid < 256) {
    ib = (long)(b0 + row) * SEQT;
    *(bf16x8*)&xL[0][row][ch * 8] = ld8(item_emb, (long)ids[ib] * 128 + ch * 8);
    pf1 = ld8(item_emb, (long)ids[ib + 1] * 128 + ch * 8);   // x_1
    idA = ids[ib + 2];                                        // for issuing x_2 at t=0
  }
  float hreg[4] = {0.f, 0.f, 0.f, 0.f};
  const f32x4 z4 = {0.f, 0.f, 0.f, 0.f};
  __syncthreads();

#define GRU_STEP(P, pfI, pfC, idU, idL)                                        \
  {                                                                            \
    const int tt = t + (P);                                                    \
    if (tid < 256) {                                                           \
      if (tt + 2 < SEQT) pfI = ld8(item_emb, (long)idU * 128 + ch * 8);        \
      if (tt + 3 < SEQT) idL = ids[ib + tt + 3];                               \
      if (tt) {                                                                \
        bf16x8 hv8 = *(const bf16x8*)&hA[P][row][ch * 8];                      \
        *(bf16x8*)(hs + ((long)(b0 + row) * SEQT + (tt - 1)) * 128 + ch * 8) = hv8; \
      }                                                                        \
    }                                                                          \
    bf16x8 af[4], xfr[4];                                                      \
    _Pragma("unroll")                                                          \
    for (int k = 0; k < 4; k++) {                                              \
      af[k] = *(const bf16x8*)&hA[P][l15][k * 32 + quad * 8];                  \
      xfr[k] = *(const bf16x8*)&xL[P][l15][k * 32 + quad * 8];                 \
    }                                                                          \
    f32x4 arx = z4, arh = z4, azx = z4, azh = z4, axn = z4, ahn = z4;          \
    _Pragma("unroll")                                                          \
    for (int k = 0; k < 4; k++) {                                              \
      arx = MFMA16(xfr[k], wir[k], arx);                                       \
      arh = MFMA16(af[k], whr[k], arh);                                        \
      azx = MFMA16(xfr[k], wiz[k], azx);                                       \
      azh = MFMA16(af[k], whz[k], azh);                                        \
      axn = MFMA16(xfr[k], win_[k], axn);                                      \
      ahn = MFMA16(af[k], whn[k], ahn);                                        \
    }                                                                          \
    _Pragma("unroll")                                                          \
    for (int r = 0; r < 4; r++) {                                              \
      float r_ = sigm(arx[r] + arh[r] + br_s);                                 \
      float z_ = sigm(azx[r] + azh[r] + bz_s);                                 \
      float n_ = tanh_fast(axn[r] + bxn_s + r_ * (ahn[r] + bhn_s));            \
      float hnew = (1.0f - z_) * n_ + z_ * hreg[r];                            \
      hreg[r] = hnew;                                                          \
      hA[(P) ^ 1][quad * 4 + r][nc] = (bf16)hnew;                              \
    }                                                                          \
    if (tid < 256 && tt + 1 < SEQT) *(bf16x8*)&xL[(P) ^ 1][row][ch * 8] = pfC; \
    bar_lgkm();                                                                \
  }

  for (int t = 0; t < SEQT; t += 2) {
    GRU_STEP(0, pf0, pf1, idA, idB)
    GRU_STEP(1, pf1, pf0, idB, idA)
  }
#undef GRU_STEP
  if (tid < 256) {
    bf16x8 hv8 = *(const bf16x8*)&hA[SEQT & 1][row][ch * 8];
    *(bf16x8*)(hs + ((long)(b0 + row) * SEQT + (SEQT - 1)) * 128 + ch * 8) = hv8;
  }
}
__global__ __launch_bounds__(512) void k_gru(
    const unsigned* __restrict__ disc, const int* ids, const void* item_emb,
    const void* wih, const void* whh, const void* bih, const void* bhh, bf16* hs) {
  __shared__ bf16 xL[2][16][136];
  __shared__ bf16 hA[2][16][136];
  if (*disc == F32_ONE)
    gru_body<float>(ids, (const float*)item_emb, (const float*)wih, (const float*)whh,
                    (const float*)bih, (const float*)bhh, hs, xL, hA);
  else
    gru_body<bf16>(ids, (const bf16*)item_emb, (const bf16*)wih, (const bf16*)whh,
                   (const bf16*)bih, (const bf16*)bhh, hs, xL, hA);
}

// ---------------------------------------------------------------------------
// aux head: grid (4, 64); stage w1 once, loop 16 batch rows per block.
// ---------------------------------------------------------------------------
template <typename DT>
__device__ __forceinline__ void aux_body(
    const bf16* __restrict__ hs, const DT* __restrict__ w1, const DT* __restrict__ b1v,
    const DT* __restrict__ w2v, const DT* __restrict__ b2v, float* __restrict__ outaux,
    bf16 (*As)[136], bf16 (*Ws)[136]) {
  const int bg = blockIdx.y;
  const int t0 = blockIdx.x * 64;
  const int tid = threadIdx.x;
  const int w = tid >> 6, lane = tid & 63, l15 = lane & 15, quad = lane >> 4;
#pragma unroll
  for (int j = 0; j < 8; j++) {
    int ci = j * 256 + tid;
    int row = ci >> 4, k8 = (ci & 15) * 8;
    *(bf16x8*)&Ws[row][k8] = ld8(w1, (long)row * 128 + k8);
  }
  float b1c[8], w2c[8];
#pragma unroll
  for (int nt = 0; nt < 8; nt++) {
    int n = nt * 16 + l15;
    b1c[nt] = ldf(b1v, n);
    w2c[nt] = ldf(w2v, n);
  }
  const float b2 = ldf(b2v, 0);
  const f32x4 z4 = {0.f, 0.f, 0.f, 0.f};
  __syncthreads();

  for (int bi = 0; bi < 16; bi++) {
    const int b = bg * 16 + bi;
#pragma unroll
    for (int j = 0; j < 4; j++) {
      int ci = j * 256 + tid;
      int row = ci >> 4, k8 = (ci & 15) * 8;
      int t = t0 + row; int tc = t < 199 ? t : 198;
      *(bf16x8*)&As[row][k8] = *(const bf16x8*)(hs + ((long)b * SEQT + tc) * 128 + k8);
    }
    bar_lgkm();
    bf16x8 af[4];
#pragma unroll
    for (int k = 0; k < 4; k++) af[k] = *(const bf16x8*)&As[w * 16 + l15][k * 32 + quad * 8];
    float part[4] = {0.f, 0.f, 0.f, 0.f};
#pragma unroll
    for (int nt = 0; nt < 8; nt++) {
      f32x4 acc = z4;
#pragma unroll
      for (int k = 0; k < 4; k++) {
        bf16x8 bfr = *(const bf16x8*)&Ws[nt * 16 + l15][k * 32 + quad * 8];
        acc = MFMA16(af[k], bfr, acc);
      }
#pragma unroll
      for (int r = 0; r < 4; r++) {
        float y = acc[r] + b1c[nt];
        part[r] += (y > 0.f ? y : 0.f) * w2c[nt];
      }
    }
#pragma unroll
    for (int m = 1; m < 16; m <<= 1)
#pragma unroll
      for (int r = 0; r < 4; r++) part[r] += __shfl_xor(part[r], m, 64);
    if (l15 == 0) {
#pragma unroll
      for (int r = 0; r < 4; r++) {
        int t = t0 + w * 16 + quad * 4 + r;
        if (t < 199) outaux[(long)b * 199 + t] = part[r] + b2;
      }
    }
    bar_lgkm();
  }
}
__global__ __launch_bounds__(256) void k_aux(
    const unsigned* __restrict__ disc, const bf16* hs, const void* w1, const void* b1v,
    const void* w2v, const void* b2v, float* outaux) {
  __shared__ bf16 As[64][136];
  __shared__ bf16 Ws[128][136];
  if (*disc == F32_ONE)
    aux_body<float>(hs, (const float*)w1, (const float*)b1v, (const float*)w2v,
                    (const float*)b2v, outaux, As, Ws);
  else
    aux_body<bf16>(hs, (const bf16*)w1, (const bf16*)b1v, (const bf16*)w2v,
                   (const bf16*)b2v, outaux, As, Ws);
}

// ---------------------------------------------------------------------------
// attention scores: grid (4, 64); stage w1 once, loop 16 batch rows per block.
// ---------------------------------------------------------------------------
template <typename DT>
__device__ __forceinline__ void att_body(
    const bf16* __restrict__ hs, const bf16* __restrict__ cand,
    const DT* __restrict__ w1, const DT* __restrict__ b1v, const DT* __restrict__ a_s,
    const DT* __restrict__ w2v, const DT* __restrict__ b2v, float* __restrict__ scores,
    bf16 (*As)[392], bf16 (*Ws)[392]) {
  const int bg = blockIdx.y;
  const int t0 = blockIdx.x * 64;
  const int tid = threadIdx.x;
  const int w = tid >> 6, lane = tid & 63, l15 = lane & 15, quad = lane >> 4;
#pragma unroll
  for (int j = 0; j < 12; j++) {
    int ci = j * 256 + tid;
    int row = ci / 48;
    int k8 = (ci % 48) * 8;
    *(bf16x8*)&Ws[row][k8] = ld8(w1, (long)row * 384 + k8);
  }
  const float aP = ldf(a_s, 0);
  const float b2 = ldf(b2v, 0);
  float b1c[4], w2c[4];
#pragma unroll
  for (int nt = 0; nt < 4; nt++) {
    int n = nt * 16 + l15;
    b1c[nt] = ldf(b1v, n);
    w2c[nt] = ldf(w2v, n);
  }
  const f32x4 z4 = {0.f, 0.f, 0.f, 0.f};
  __syncthreads();

  for (int bi = 0; bi < 16; bi++) {
    const int b = bg * 16 + bi;
#pragma unroll
    for (int j = 0; j < 12; j++) {
      int ci = j * 256 + tid;
      int row = ci / 48;
      int k8 = (ci % 48) * 8;
      int t = t0 + row; int tc = t < SEQT ? t : SEQT - 1;
      const bf16* hrow = hs + ((long)b * SEQT + tc) * 128;
      bf16x8 v;
      if (k8 < 128) v = *(const bf16x8*)(hrow + k8);
      else if (k8 < 256) v = *(const bf16x8*)(cand + b * 128 + (k8 - 128));
      else {
        bf16x8 hv = *(const bf16x8*)(hrow + (k8 - 256));
        bf16x8 cv = *(const bf16x8*)(cand + b * 128 + (k8 - 256));
#pragma unroll
        for (int q = 0; q < 8; q++) v[q] = (bf16)((float)hv[q] * (float)cv[q]);
      }
      *(bf16x8*)&As[row][k8] = v;
    }
    bar_lgkm();
    f32x4 acc[4] = {z4, z4, z4, z4};
    for (int k = 0; k < 12; k++) {
      bf16x8 af = *(const bf16x8*)&As[w * 16 + l15][k * 32 + quad * 8];
#pragma unroll
      for (int nt = 0; nt < 4; nt++) {
        bf16x8 bfr = *(const bf16x8*)&Ws[nt * 16 + l15][k * 32 + quad * 8];
        acc[nt] = MFMA16(af, bfr, acc[nt]);
      }
    }
    float part[4] = {0.f, 0.f, 0.f, 0.f};
#pragma unroll
    for (int nt = 0; nt < 4; nt++) {
#pragma unroll
      for (int r = 0; r < 4; r++) {
        float y = acc[nt][r] + b1c[nt];
        y = (y >= 0.f) ? y : aP * y;
        part[r] += y * w2c[nt];
      }
    }
#pragma unroll
    for (int m = 1; m < 16; m <<= 1)
#pragma unroll
      for (int r = 0; r < 4; r++) part[r] += __shfl_xor(part[r], m, 64);
    if (l15 == 0) {
#pragma unroll
      for (int r = 0; r < 4; r++) {
        int t = t0 + w * 16 + quad * 4 + r;
        if (t < SEQT) scores[(long)b * SEQT + t] = part[r] + b2;
      }
    }
    bar_lgkm();
  }
}
__global__ __launch_bounds__(256) void k_att(
    const unsigned* __restrict__ disc, const bf16* hs, const bf16* cand,
    const void* w1, const void* b1v, const void* a_s,
    const void* w2v, const void* b2v, float* scores) {
  __shared__ bf16 As[64][392];
  __shared__ bf16 Ws[64][392];
  if (*disc == F32_ONE)
    att_body<float>(hs, cand, (const float*)w1, (const float*)b1v, (const float*)a_s,
                    (const float*)w2v, (const float*)b2v, scores, As, Ws);
  else
    att_body<bf16>(hs, cand, (const bf16*)w1, (const bf16*)b1v, (const bf16*)a_s,
                   (const bf16*)w2v, (const bf16*)b2v, scores, As, Ws);
}

// ---------------------------------------------------------------------------
// softmax over T=200, in place on fp32 scores.
// ---------------------------------------------------------------------------
__global__ __launch_bounds__(256) void k_softmax(float* __restrict__ sc) {
  const int b = blockIdx.x, tid = threadIdx.x;
  __shared__ float red[256];
  float v = (tid < SEQT) ? sc[(long)b * SEQT + tid] : -1e30f;
  red[tid] = v; __syncthreads();
  for (int s = 128; s > 0; s >>= 1) { if (tid < s) red[tid] = fmaxf(red[tid], red[tid + s]); __syncthreads(); }
  float mx = red[0]; __syncthreads();
  float e = (tid < SEQT) ? __expf(v - mx) : 0.f;
  red[tid] = e; __syncthreads();
  for (int s = 128; s > 0; s >>= 1) { if (tid < s) red[tid] += red[tid + s]; __syncthreads(); }
  float inv = 1.0f / red[0];
  if (tid < SEQT) sc[(long)b * SEQT + tid] = e * inv;
}

// ---------------------------------------------------------------------------
// AUGRU scan: 2 lgkm barriers/step, distance-2 prefetch, gates in registers.
// ---------------------------------------------------------------------------
template <typename DT>
__device__ __forceinline__ void augru_body(
    const bf16* __restrict__ hsrc, const float* __restrict__ att,
    const DT* __restrict__ wz, const DT* __restrict__ wr, const DT* __restrict__ wh,
    const DT* __restrict__ bzv, const DT* __restrict__ brv, const DT* __restrict__ bhv,
    bf16* __restrict__ xf_out,
    bf16 (*xA)[16][136], bf16 (*hA)[16][136], bf16 (*rhA)[136], float (*attL)[201]) {
  const int b0 = blockIdx.x * 16;
  const int tid = threadIdx.x;
  const int w = tid >> 6, lane = tid & 63, l15 = lane & 15, quad = lane >> 4;
  const int nc = w * 16 + l15;

  for (int i = tid; i < 2 * 16 * 136; i += 512) ((bf16*)hA)[i] = (bf16)0.0f;
  for (int i = tid; i < 16 * SEQT; i += 512) {
    int r = i / SEQT, c = i - r * SEQT;
    attL[r][c] = att[(long)(b0 + r) * SEQT + c];
  }

  bf16x8 wzx[4], wzh[4], wrx[4], wrh[4], whx[4], whh_[4];
#pragma unroll
  for (int k = 0; k < 4; k++) {
    const long off = k * 32 + quad * 8;
    wzx[k] = ld8(wz, (long)nc * 256 + off);
    wzh[k] = ld8(wz, (long)nc * 256 + 128 + off);
    wrx[k] = ld8(wr, (long)nc * 256 + off);
    wrh[k] = ld8(wr, (long)nc * 256 + 128 + off);
    whx[k] = ld8(wh, (long)nc * 256 + off);
    whh_[k] = ld8(wh, (long)nc * 256 + 128 + off);
  }
  const float bz_s = ldf(bzv, nc);
  const float br_s = ldf(brv, nc);
  const float bh_s = ldf(bhv, nc);

  const int row = tid >> 4, ch = tid & 15;
  bf16x8 pf0, pf1;
  if (tid < 256) {
    *(bf16x8*)&xA[0][row][ch * 8] =
        *(const bf16x8*)(hsrc + ((long)(b0 + row) * SEQT) * 128 + ch * 8);
    pf1 = *(const bf16x8*)(hsrc + ((long)(b0 + row) * SEQT + 1) * 128 + ch * 8);
  }
  float hreg[4] = {0.f, 0.f, 0.f, 0.f};
  const f32x4 z4 = {0.f, 0.f, 0.f, 0.f};
  __syncthreads();

#define AUGRU_STEP(P, pfI, pfC)                                                \
  {                                                                            \
    const int tt = t + (P);                                                    \
    if (tid < 256 && tt + 2 < SEQT)                                            \
      pfI = *(const bf16x8*)(hsrc + ((long)(b0 + row) * SEQT + tt + 2) * 128 + ch * 8); \
    bf16x8 af[4], xfr[4];                                                      \
    _Pragma("unroll")                                                          \
    for (int k = 0; k < 4; k++) {                                              \
      af[k] = *(const bf16x8*)&hA[P][l15][k * 32 + quad * 8];                  \
      xfr[k] = *(const bf16x8*)&xA[P][l15][k * 32 + quad * 8];                 \
    }                                                                          \
    f32x4 azx = z4, azh = z4, arx = z4, arh = z4, axh = z4;                    \
    _Pragma("unroll")                                                          \
    for (int k = 0; k < 4; k++) {                                              \
      azx = MFMA16(xfr[k], wzx[k], azx);                                       \
      azh = MFMA16(af[k], wzh[k], azh);                                        \
      arx = MFMA16(xfr[k], wrx[k], arx);                                       \
      arh = MFMA16(af[k], wrh[k], arh);                                        \
      axh = MFMA16(xfr[k], whx[k], axh);                                       \
    }                                                                          \
    float zp[4];                                                               \
    _Pragma("unroll")                                                          \
    for (int r = 0; r < 4; r++) {                                              \
      float a_ = attL[quad * 4 + r][tt];                                       \
      float z_ = sigm(azx[r] + azh[r] + bz_s);                                 \
      float r_ = sigm(arx[r] + arh[r] + br_s);                                 \
      zp[r] = a_ * z_;                                                         \
      rhA[quad * 4 + r][nc] = (bf16)(r_ * hreg[r]);                            \
    }                                                                          \
    bar_lgkm();                                                                \
    bf16x8 rf[4];                                                              \
    _Pragma("unroll")                                                          \
    for (int k = 0; k < 4; k++) rf[k] = *(const bf16x8*)&rhA[l15][k * 32 + quad * 8]; \
    f32x4 ahh = z4;                                                            \
    _Pragma("unroll")                                                          \
    for (int k = 0; k < 4; k++) ahh = MFMA16(rf[k], whh_[k], ahh);             \
    _Pragma("unroll")                                                          \
    for (int r = 0; r < 4; r++) {                                              \
      float ht = tanh_fast(axh[r] + bh_s + ahh[r]);                            \
      float hnew = (1.f - zp[r]) * hreg[r] + zp[r] * ht;                       \
      hreg[r] = hnew;                                                          \
      hA[(P) ^ 1][quad * 4 + r][nc] = (bf16)hnew;                              \
    }                                                                          \
    if (tid < 256 && tt + 1 < SEQT) *(bf16x8*)&xA[(P) ^ 1][row][ch * 8] = pfC; \
    bar_lgkm();                                                                \
  }

  for (int t = 0; t < SEQT; t += 2) {
    AUGRU_STEP(0, pf0, pf1)
    AUGRU_STEP(1, pf1, pf0)
  }
#undef AUGRU_STEP
#pragma unroll
  for (int r = 0; r < 4; r++)
    xf_out[(long)(b0 + quad * 4 + r) * 352 + nc] = (bf16)hreg[r];
}
__global__ __launch_bounds__(512) void k_augru(
    const unsigned* __restrict__ disc, const bf16* hsrc, const float* att,
    const void* wz, const void* wr, const void* wh,
    const void* bzv, const void* brv, const void* bhv, bf16* xf_out) {
  __shared__ bf16 xA[2][16][136];
  __shared__ bf16 hA[2][16][136];
  __shared__ bf16 rhA[16][136];
  __shared__ float attL[16][201];
  if (*disc == F32_ONE)
    augru_body<float>(hsrc, att, (const float*)wz, (const float*)wr, (const float*)wh,
                      (const float*)bzv, (const float*)brv, (const float*)bhv, xf_out,
                      xA, hA, rhA, attL);
  else
    augru_body<bf16>(hsrc, att, (const bf16*)wz, (const bf16*)wr, (const bf16*)wh,
                     (const bf16*)bzv, (const bf16*)brv, (const bf16*)bhv, xf_out,
                     xA, hA, rhA, attL);
}

// ---------------------------------------------------------------------------
// final MLP: 352->256->128->64 (LN+prelu each) -> 3 heads (sigmoid, fp32 out).
// ---------------------------------------------------------------------------
template <typename DT>
__device__ __forceinline__ void mlp_body(
    const bf16* __restrict__ xf,
    const DT* __restrict__ w1, const DT* __restrict__ b1, const DT* __restrict__ g1, const DT* __restrict__ be1, const DT* __restrict__ pa1,
    const DT* __restrict__ w2, const DT* __restrict__ b2, const DT* __restrict__ g2, const DT* __restrict__ be2, const DT* __restrict__ pa2,
    const DT* __restrict__ w3, const DT* __restrict__ b3, const DT* __restrict__ g3, const DT* __restrict__ be3, const DT* __restrict__ pa3,
    const DT* __restrict__ hw, const DT* __restrict__ hb, float* __restrict__ preds,
    float (*xs)[352], float (*ys)[256]) {
  const int tid = threadIdx.x, w = tid >> 6, lane = tid & 63;
  const int b = blockIdx.x * 4 + w;
  for (int i = lane; i < 352; i += 64) xs[w][i] = (float)xf[(long)b * 352 + i];
  __syncthreads();
  float acc1[4];
#pragma unroll
  for (int oi = 0; oi < 4; oi++) {
    int o = lane + 64 * oi;
    float s = ldf(b1, o);
    for (int k = 0; k < 352; k += 8) {
      bf16x8 wv = ld8(w1, (long)o * 352 + k);
#pragma unroll
      for (int j = 0; j < 8; j++) s += xs[w][k + j] * (float)wv[j];
    }
    acc1[oi] = s;
  }
  float sm = acc1[0] + acc1[1] + acc1[2] + acc1[3];
#pragma unroll
  for (int m = 1; m < 64; m <<= 1) sm += __shfl_xor(sm, m, 64);
  float mean = sm * (1.0f / 256.0f);
  float vs = 0.f;
#pragma unroll
  for (int oi = 0; oi < 4; oi++) { float d = acc1[oi] - mean; vs += d * d; }
#pragma unroll
  for (int m = 1; m < 64; m <<= 1) vs += __shfl_xor(vs, m, 64);
  float rstd = rsqrtf(vs * (1.0f / 256.0f) + 1e-5f);
  float a1 = ldf(pa1, 0);
#pragma unroll
  for (int oi = 0; oi < 4; oi++) {
    int o = lane + 64 * oi;
    float y = (acc1[oi] - mean) * rstd * ldf(g1, o) + ldf(be1, o);
    ys[w][o] = (y >= 0.f) ? y : a1 * y;
  }
  __syncthreads();
  float acc2[2];
#pragma unroll
  for (int oi = 0; oi < 2; oi++) {
    int o = lane + 64 * oi;
    float s = ldf(b2, o);
    for (int k = 0; k < 256; k += 8) {
      bf16x8 wv = ld8(w2, (long)o * 256 + k);
#pragma unroll
      for (int j = 0; j < 8; j++) s += ys[w][k + j] * (float)wv[j];
    }
    acc2[oi] = s;
  }
  sm = acc2[0] + acc2[1];
#pragma unroll
  for (int m = 1; m < 64; m <<= 1) sm += __shfl_xor(sm, m, 64);
  mean = sm * (1.0f / 128.0f);
  vs = 0.f;
#pragma unroll
  for (int oi = 0; oi < 2; oi++) { float d = acc2[oi] - mean; vs += d * d; }
#pragma unroll
  for (int m = 1; m < 64; m <<= 1) vs += __shfl_xor(vs, m, 64);
  rstd = rsqrtf(vs * (1.0f / 128.0f) + 1e-5f);
  float a2 = ldf(pa2, 0);
  __syncthreads();
#pragma unroll
  for (int oi = 0; oi < 2; oi++) {
    int o = lane + 64 * oi;
    float y = (acc2[oi] - mean) * rstd * ldf(g2, o) + ldf(be2, o);
    xs[w][o] = (y >= 0.f) ? y : a2 * y;
  }
  __syncthreads();
  float s3 = ldf(b3, lane);
  for (int k = 0; k < 128; k += 8) {
    bf16x8 wv = ld8(w3, (long)lane * 128 + k);
#pragma unroll
    for (int j = 0; j < 8; j++) s3 += xs[w][k + j] * (float)wv[j];
  }
  sm = s3;
#pragma unroll
  for (int m = 1; m < 64; m <<= 1) sm += __shfl_xor(sm, m, 64);
  mean = sm * (1.0f / 64.0f);
  float d3 = s3 - mean;
  vs = d3 * d3;
#pragma unroll
  for (int m = 1; m < 64; m <<= 1) vs += __shfl_xor(vs, m, 64);
  rstd = rsqrtf(vs * (1.0f / 64.0f) + 1e-5f);
  float a3 = ldf(pa3, 0);
  float y3 = d3 * rstd * ldf(g3, lane) + ldf(be3, lane);
  y3 = (y3 >= 0.f) ? y3 : a3 * y3;
  ys[w][lane] = y3;
  __syncthreads();
  if (lane < 3) {
    float s = ldf(hb, lane);
    for (int k = 0; k < 64; k++) s += ys[w][k] * ldf(hw, lane * 64 + k);
    preds[(long)b * 3 + lane] = sigm(s);
  }
}
__global__ __launch_bounds__(256) void k_mlp(
    const unsigned* __restrict__ disc, const bf16* xf,
    const void* w1, const void* b1, const void* g1, const void* be1, const void* pa1,
    const void* w2, const void* b2, const void* g2, const void* be2, const void* pa2,
    const void* w3, const void* b3, const void* g3, const void* be3, const void* pa3,
    const void* hw, const void* hb, float* preds) {
  __shared__ float xs[4][352];
  __shared__ float ys[4][256];
  if (*disc == F32_ONE)
    mlp_body<float>(xf,
        (const float*)w1, (const float*)b1, (const float*)g1, (const float*)be1, (const float*)pa1,
        (const float*)w2, (const float*)b2, (const float*)g2, (const float*)be2, (const float*)pa2,
        (const float*)w3, (const float*)b3, (const float*)g3, (const float*)be3, (const float*)pa3,
        (const float*)hw, (const float*)hb, preds, xs, ys);
  else
    mlp_body<bf16>(xf,
        (const bf16*)w1, (const bf16*)b1, (const bf16*)g1, (const bf16*)be1, (const bf16*)pa1,
        (const bf16*)w2, (const bf16*)b2, (const bf16*)g2, (const bf16*)be2, (const bf16*)pa2,
        (const bf16*)w3, (const bf16*)b3, (const bf16*)g3, (const bf16*)be3, (const bf16*)pa3,
        (const bf16*)hw, (const bf16*)hb, preds, xs, ys);
}

// ---------------------------------------------------------------------------
extern "C" void kernel_launch(void* const* d_in, const int* in_sizes, int n_in,
                              void* d_out, int out_size, void* d_ws, size_t ws_size,
                              hipStream_t stream) {
  const int* behavior_ids = (const int*)d_in[0];
  const int* candidate_id = (const int*)d_in[1];
  const int* candidate_cat = (const int*)d_in[2];
  const void* dense = d_in[3];
  const void* item_emb = d_in[4];
  const void* cat_emb = d_in[5];
  const void* gru_wih = d_in[6];
  const void* gru_whh = d_in[7];
  const void* gru_bih = d_in[8];
  const void* gru_bhh = d_in[9];
  const void* aux_w1 = d_in[10];
  const void* aux_b1 = d_in[11];
  const void* aux_w2 = d_in[12];
  const void* aux_b2 = d_in[13];
  const void* att_w1 = d_in[14];
  const void* att_b1 = d_in[15];
  const void* att_a = d_in[16];
  const void* att_w2 = d_in[17];
  const void* att_b2 = d_in[18];
  const void* wz = d_in[19];
  const void* bz = d_in[20];
  const void* wr = d_in[21];
  const void* br = d_in[22];
  const void* wh = d_in[23];
  const void* bh = d_in[24];
  const void* dp_w = d_in[25];
  const void* dp_b = d_in[26];
  const void* m_w1 = d_in[27];
  const void* m_b1 = d_in[28];
  const void* ln_g1 = d_in[29];   // ones -> dtype discriminator
  const void* ln_b1 = d_in[30];
  const void* pa1 = d_in[31];
  const void* m_w2 = d_in[32];
  const void* m_b2 = d_in[33];
  const void* ln_g2 = d_in[34];
  const void* ln_b2 = d_in[35];
  const void* pa2 = d_in[36];
  const void* m_w3 = d_in[37];
  const void* m_b3 = d_in[38];
  const void* ln_g3 = d_in[39];
  const void* ln_b3 = d_in[40];
  const void* pa3 = d_in[41];
  const void* heads_w = d_in[42];
  const void* heads_b = d_in[43];
  (void)in_sizes; (void)n_in; (void)out_size; (void)ws_size;

  const unsigned* disc = (const unsigned*)ln_g1;

  char* ws = (char*)d_ws;
  bf16* HS = (bf16*)(ws);                        // (B,T,128) bf16   52,428,800 B
  float* SC = (float*)(ws + 52428800L);          // (B,T) fp32          819,200 B
  bf16* CAND = (bf16*)(ws + 53248000L);          // (B,128) bf16        262,144 B
  bf16* XF = (bf16*)(ws + 53510144L);            // (B,352) bf16        720,896 B
  float* OUT = (float*)d_out;                    // fp32 output

  k_prep<<<BATCH, 128, 0, stream>>>(disc, candidate_id, candidate_cat, dense, item_emb,
                                    cat_emb, dp_w, dp_b, CAND, XF);
  k_gru<<<64, 512, 0, stream>>>(disc, behavior_ids, item_emb, gru_wih, gru_whh,
                                gru_bih, gru_bhh, HS);
  k_aux<<<dim3(4, 64), 256, 0, stream>>>(disc, HS, aux_w1, aux_b1, aux_w2, aux_b2, OUT + 3072);
  k_att<<<dim3(4, 64), 256, 0, stream>>>(disc, HS, CAND, att_w1, att_b1, att_a, att_w2, att_b2, SC);
  k_softmax<<<BATCH, 256, 0, stream>>>(SC);
  k_augru<<<64, 512, 0, stream>>>(disc, HS, SC, wz, wr, wh, bz, br, bh, XF);
  k_mlp<<<256, 256, 0, stream>>>(disc, XF,
      m_w1, m_b1, ln_g1, ln_b1, pa1,
      m_w2, m_b2, ln_g2, ln_b2, pa2,
      m_w3, m_b3, ln_g3, ln_b3, pa3,
      heads_w, heads_b, OUT);
}